// Round 5
// baseline (980.707 us; speedup 1.0000x reference)
//
#include <hip/hip_runtime.h>
#include <math.h>

#define NB 8192
#define IND 512
#define QDIM 128
#define CD 1024
#define KE 8
#define PD 64
#define PCAP 160  // compact-list capacity per row (covers sparsity levels 5,150)

typedef _Float16 h8 __attribute__((ext_vector_type(8)));
typedef _Float16 h4 __attribute__((ext_vector_type(4)));
typedef float fx16 __attribute__((ext_vector_type(16)));

__device__ __forceinline__ float softt(float v, float th) {
    float a = fabsf(v) - th;
    return a > 0.0f ? copysignf(a, v) : 0.0f;
}

// ---------------- split helpers: v = hi + lo * 2^-11 (lo stored pre-scaled by 2048)
__device__ __forceinline__ void fsplit(float v, _Float16& hi, _Float16& lo) {
    hi = (_Float16)v;
    lo = (_Float16)((v - (float)hi) * 2048.0f);
}

// ---------------- K0: M = Wq @ keys^T / sqrt(QDIM), sb = bq @ keys^T / sqrt(QDIM)
__global__ void k_precompute_M(const float* __restrict__ Wq, const float* __restrict__ keys,
                               const float* __restrict__ bq, float* __restrict__ M,
                               float* __restrict__ sb) {
    const float RSQ = 0.088388347648318447f; // 1/sqrt(128)
    int g = blockIdx.x * 256 + threadIdx.x;  // 0..4095
    if (g < IND * KE) {
        int i = g >> 3, k = g & 7;
        float s = 0.f;
        for (int q = 0; q < QDIM; ++q) s += Wq[i * QDIM + q] * keys[k * QDIM + q];
        M[g] = s * RSQ;  // M[i*8+k]
    }
    if (blockIdx.x == 0 && threadIdx.x < KE) {
        int k = threadIdx.x;
        float s = 0.f;
        for (int q = 0; q < QDIM; ++q) s += bq[q] * keys[k * QDIM + q];
        sb[k] = s * RSQ;
    }
}

// ---------------- K1: per-row scores -> expert idx (one wave per row, no atomics)
__global__ __launch_bounds__(256)
void k_scores(const float* __restrict__ x, const float* __restrict__ M,
              const float* __restrict__ sb, int* __restrict__ idx) {
    __shared__ float Ms[KE][IND];
    __shared__ float sbs[KE];
    int t = threadIdx.x;
    #pragma unroll
    for (int j = 0; j < 16; ++j) {
        int e = j * 256 + t;
        Ms[e & 7][e >> 3] = M[e];
    }
    if (t < KE) sbs[t] = sb[t];
    __syncthreads();
    int w = t >> 6, lane = t & 63;
    int row = blockIdx.x * 4 + w;
    const float* xr = x + (size_t)row * IND;
    float sc[KE];
    #pragma unroll
    for (int k = 0; k < KE; ++k) sc[k] = 0.f;
    #pragma unroll
    for (int j = 0; j < IND / 64; ++j) {
        int ii = lane + 64 * j;
        float xv = xr[ii];
        #pragma unroll
        for (int k = 0; k < KE; ++k) sc[k] += xv * Ms[k][ii];
    }
    #pragma unroll
    for (int k = 0; k < KE; ++k) {
        #pragma unroll
        for (int off = 32; off >= 1; off >>= 1) sc[k] += __shfl_down(sc[k], off, 64);
    }
    if (lane == 0) {
        float smax = -1e30f;
        #pragma unroll
        for (int k = 0; k < KE; ++k) { sc[k] += sbs[k]; smax = fmaxf(smax, sc[k]); }
        const float LN09 = -0.105360515657826301f;  // ln(0.9)
        int e = 0;
        #pragma unroll
        for (int k = KE - 1; k >= 0; --k)
            if (sc[k] >= smax + LN09) e = k;  // smallest eligible k (sl is increasing)
        idx[row] = e;
    }
}

// ---------------- K2: single-block counting sort: counts, offsets, perm (no global atomics)
__global__ __launch_bounds__(256)
void k_count(const int* __restrict__ idx, int* __restrict__ perm,
             int* __restrict__ counts, int* __restrict__ offsets) {
    __shared__ int hist[256][KE];      // 8 KB
    __shared__ int sc[2][KE][256];     // 16 KB ping-pong scan
    __shared__ int base[KE];
    const int t = threadIdx.x;
    int pc[KE];
    #pragma unroll
    for (int e = 0; e < KE; ++e) pc[e] = 0;
    for (int j = 0; j < NB / 256; ++j) pc[idx[j * 256 + t]]++;
    #pragma unroll
    for (int e = 0; e < KE; ++e) { hist[t][e] = pc[e]; sc[0][e][t] = pc[e]; }
    __syncthreads();
    int cur = 0;
    for (int d = 1; d < 256; d <<= 1) {
        #pragma unroll
        for (int e = 0; e < KE; ++e) {
            int v = sc[cur][e][t];
            if (t >= d) v += sc[cur][e][t - d];
            sc[cur ^ 1][e][t] = v;
        }
        cur ^= 1;
        __syncthreads();
    }
    if (t == 0) {
        int a = 0;
        #pragma unroll
        for (int e = 0; e < KE; ++e) {
            int tot = sc[cur][e][255];
            base[e] = a; offsets[e] = a; counts[e] = tot; a += tot;
        }
    }
    __syncthreads();
    int pos[KE];
    #pragma unroll
    for (int e = 0; e < KE; ++e) pos[e] = base[e] + sc[cur][e][t] - hist[t][e];
    for (int j = 0; j < NB / 256; ++j) {
        int r = j * 256 + t;
        int e = idx[r];
        perm[pos[e]++] = r;
    }
}

// ---------------- K4: elementwise split of x into hi/lo fp16 planes
__global__ __launch_bounds__(256)
void k_split_rows(const float* __restrict__ src, _Float16* __restrict__ ph,
                  _Float16* __restrict__ pl, int n) {
    int i = (blockIdx.x * 256 + threadIdx.x) * 4;
    if (i < n) {
        float4 v = *(const float4*)(src + i);
        h4 hh, ll;
        #pragma unroll
        for (int j = 0; j < 4; ++j) {
            _Float16 a, b;
            fsplit((&v.x)[j], a, b);
            hh[j] = a; ll[j] = b;
        }
        *(h4*)(ph + i) = hh;
        *(h4*)(pl + i) = ll;
    }
}

// ---------------- K5: transpose+split: src[e][K][CD] fp32 -> th/tl[e][CD][K] fp16
// Skips experts with zero selected rows (counts from k_count — launch-ordered before).
__global__ __launch_bounds__(256)
void k_tsplit(const float* __restrict__ src, _Float16* __restrict__ th,
              _Float16* __restrict__ tl, int K, const int* __restrict__ counts) {
    int e = blockIdx.z;
    if (counts[e] == 0) return;  // expert never used downstream
    __shared__ float tile[64][65];
    int k0 = blockIdx.x * 64;
    int n0 = blockIdx.y * 64;
    const float* s = src + (size_t)e * K * CD;
    int t = threadIdx.x;
    int tr = t >> 4;
    int tc = (t & 15) * 4;
    #pragma unroll
    for (int p = 0; p < 4; ++p) {
        int kk = tr + p * 16;
        float4 v = *(const float4*)&s[(size_t)(k0 + kk) * CD + n0 + tc];
        #pragma unroll
        for (int j = 0; j < 4; ++j) tile[kk][tc + j] = (&v.x)[j];
    }
    __syncthreads();
    int n = t >> 2;
    int kq = (t & 3) * 16;
    h8 hh0, hh1, ll0, ll1;
    #pragma unroll
    for (int j = 0; j < 8; ++j) {
        _Float16 a, b;
        fsplit(tile[kq + j][n], a, b);
        hh0[j] = a; ll0[j] = b;
        fsplit(tile[kq + 8 + j][n], a, b);
        hh1[j] = a; ll1[j] = b;
    }
    size_t ob = ((size_t)e * CD + n0 + n) * K + k0 + kq;
    *(h8*)(th + ob) = hh0;
    *(h8*)(th + ob + 8) = hh1;
    *(h8*)(tl + ob) = ll0;
    *(h8*)(tl + ob + 8) = ll1;
}

// ---------------- grouped split-fp16 MFMA GEMM, 128x128 tile — LDS-FREE direct form.
// [R5] Occupancy is grid-limited (512 working blocks = 2 blocks/CU = 8 waves/CU),
// so barrier drains can't be hidden by TLP (R2/R4 evidence: MfmaUtil stuck <29%).
// Key realization: LDS staging is pointless here — B (S planes, 4MB) is
// L2-resident; A (32MB) is L2-PARTITIONED by the XCD swizzle (each XCD's byl
// slice = 4MB = its L2). A is [row][K], B is [col][K]: the MFMA fragment
// (lane: row/col=ml, k=q*8..q*8+7) is a contiguous 16B h8 global load.
// So: zero LDS, zero barriers, zero waitcnt drains — pure load+MFMA stream;
// compiler pipelines deeply (no barrier kills vmcnt depth), 256-VGPR budget
// via __launch_bounds__(256,2) (grid caps us at 2 blocks/CU anyway).
// Single accumulator via exact 2^-11 operand pre-scale (R3, absmax-verified).
template <int KDIM, int MODE>
__global__ __launch_bounds__(256, 2)
void k_mfma(const _Float16* __restrict__ Ah, const _Float16* __restrict__ Al,
            const _Float16* __restrict__ Bh, const _Float16* __restrict__ Bl,
            const float* __restrict__ theta, const float* __restrict__ BxBuf,
            float* __restrict__ BxOut, _Float16* __restrict__ zh, _Float16* __restrict__ zl,
            float* __restrict__ zf,
            const int* __restrict__ perm, const int* __restrict__ counts,
            const int* __restrict__ offsets) {
    const int e = blockIdx.z;
    const int cnt = counts[e];
    const int p = blockIdx.x + 8 * blockIdx.y;
    const int gx = p & 7;
    const int qq = p >> 3;
    const int bxl = qq & 7;
    const int byl = gx + 8 * (qq >> 3);
    const int m0 = byl * 128;
    if (m0 >= cnt) return;
    const int n0 = bxl * 128;
    const int off = offsets[e];
    const float th = theta[e];

    const int t = threadIdx.x;
    const int lane = t & 63;
    const int w = t >> 6;
    const int wm = w >> 1, wn = w & 1;
    const int q = lane >> 5;
    const int ml = lane & 31;

    // per-lane global fragment base pointers (16B h8 chunks, K-contiguous);
    // all kt offsets fold into the 13-bit signed global_load immediate (<=2KB).
    const _Float16* aP[2][2];  // [mt][hi/lo]
    #pragma unroll
    for (int mt = 0; mt < 2; ++mt) {
        int mrow = m0 + wm * 64 + mt * 32 + ml;
        if (mrow > cnt - 1) mrow = cnt - 1;
        size_t grow;
        if constexpr (MODE == 0) grow = (size_t)perm[off + mrow];
        else grow = (size_t)(off + mrow);
        aP[mt][0] = Ah + grow * KDIM + q * 8;
        aP[mt][1] = Al + grow * KDIM + q * 8;
    }
    const _Float16* bP[2][2];  // [nt][hi/lo]
    #pragma unroll
    for (int nt = 0; nt < 2; ++nt) {
        size_t col = (size_t)e * CD + n0 + wn * 64 + nt * 32 + ml;
        bP[nt][0] = Bh + col * KDIM + q * 8;
        bP[nt][1] = Bl + col * KDIM + q * 8;
    }

    fx16 acc[2][2];
    #pragma unroll
    for (int mt = 0; mt < 2; ++mt)
        #pragma unroll
        for (int nt = 0; nt < 2; ++nt)
            #pragma unroll
            for (int g = 0; g < 16; ++g) acc[mt][nt][g] = 0.f;

    const _Float16 SC = (_Float16)4.8828125e-4f;  // 2^-11, exact exponent shift

    #pragma unroll 4
    for (int ks = 0; ks < KDIM / 16; ++ks) {
        const int ko = ks * 16;
        h8 a_h[2], a_l[2], b_h[2], b_l[2];
        #pragma unroll
        for (int mt = 0; mt < 2; ++mt) {
            a_h[mt] = *(const h8*)(aP[mt][0] + ko);
            a_l[mt] = *(const h8*)(aP[mt][1] + ko);
        }
        #pragma unroll
        for (int nt = 0; nt < 2; ++nt) {
            b_h[nt] = *(const h8*)(bP[nt][0] + ko);
            b_l[nt] = *(const h8*)(bP[nt][1] + ko);
        }
        h8 ahs[2], bhs[2];
        #pragma unroll
        for (int mt = 0; mt < 2; ++mt) ahs[mt] = a_h[mt] * SC;
        #pragma unroll
        for (int nt = 0; nt < 2; ++nt) bhs[nt] = b_h[nt] * SC;
        #pragma unroll
        for (int mt = 0; mt < 2; ++mt)
            #pragma unroll
            for (int nt = 0; nt < 2; ++nt) {
                acc[mt][nt] = __builtin_amdgcn_mfma_f32_32x32x16_f16(a_h[mt], b_h[nt], acc[mt][nt], 0, 0, 0);
                acc[mt][nt] = __builtin_amdgcn_mfma_f32_32x32x16_f16(ahs[mt], b_l[nt], acc[mt][nt], 0, 0, 0);
                acc[mt][nt] = __builtin_amdgcn_mfma_f32_32x32x16_f16(a_l[mt], bhs[nt], acc[mt][nt], 0, 0, 0);
            }
    }

    // epilogue: C/D layout col=lane&31, row=(g&3)+8*(g>>2)+4*q  [m74/m101]
    #pragma unroll
    for (int mt = 0; mt < 2; ++mt)
        #pragma unroll
        for (int nt = 0; nt < 2; ++nt) {
            #pragma unroll
            for (int g = 0; g < 16; ++g) {
                int rl = wm * 64 + mt * 32 + (g & 3) + 8 * (g >> 2) + 4 * q;
                int mrow = m0 + rl;
                if (mrow < cnt) {
                    int col = n0 + wn * 64 + nt * 32 + ml;
                    size_t addr = (size_t)(off + mrow) * CD + col;
                    float v = acc[mt][nt][g];
                    if constexpr (MODE == 0) {
                        BxOut[addr] = v;
                        float z = softt(v, th);
                        _Float16 a, b;
                        fsplit(z, a, b);
                        zh[addr] = a; zl[addr] = b;
                    } else if constexpr (MODE == 1) {
                        float z = softt(v + BxBuf[addr], th);
                        _Float16 a, b;
                        fsplit(z, a, b);
                        zh[addr] = a; zl[addr] = b;
                    } else {
                        zf[addr] = softt(v + BxBuf[addr], th);
                    }
                }
            }
        }
}

// ---------------- K6+K7 fused: per-wave top-k prune + h = b1 + sparse_z@W1, then
// BLOCK-COOPERATIVE out = relu(h)@W2 + b2.
// [R1] Old per-wave W2 pass re-read all of W2 (256KB) per ROW: 8192x256KB = 2.1 GB
// L2 traffic = >=62us floor at 34.5 TB/s (kernel was 96us, VALUBusy 33%, HBM 6%).
// Now: wave w covers K-range [w*256,(w+1)*256), loads each W2 row once, applies to
// all 4 rows' hS (uniform-address LDS broadcast, conflict-free) -> 4x less L2
// traffic; 4KB LDS partials + 2nd barrier reduce across waves.
__global__ __launch_bounds__(256)
void k_po(const float* __restrict__ z, const int* __restrict__ offsets,
          const float* __restrict__ W1, const float* __restrict__ b1,
          const float* __restrict__ W2, const float* __restrict__ b2,
          const int* __restrict__ perm, float* __restrict__ out) {
    const int SL[KE] = {5, 150, 296, 441, 587, 732, 878, 1024};
    __shared__ float vLg[4][PCAP];   // 2.5 KB
    __shared__ int   iLg[4][PCAP];   // 2.5 KB
    __shared__ float hSg[4][CD];     // 16 KB; doubles as dense pruned-z staging
    __shared__ float prt[4][4][64];  // 4 KB [wave][row][lane] partial sums
    const int t = threadIdx.x;
    const int lane = t & 63;
    const int wv = t >> 6;
    const int slot = blockIdx.x * 4 + wv;
    float* vL = vLg[wv];
    int* iLs = iLg[wv];
    float* hS = hSg[wv];

    int k = 0;
    #pragma unroll
    for (int e = 1; e < KE; ++e)
        if (slot >= offsets[e]) k = e;
    const int lvl = SL[k];

    const float* zr = z + (size_t)slot * CD;
    float v[16];
    unsigned ab[16];
    #pragma unroll
    for (int j = 0; j < 16; ++j) {
        v[j] = zr[lane + 64 * j];
        ab[j] = __float_as_uint(fabsf(v[j]));
    }
    // exact kth-largest |z| bit pattern; count via ballot+popc (no shuffles)
    unsigned thr = 0;
    for (int b = 30; b >= 0; --b) {
        unsigned cand = thr | (1u << b);
        int c = 0;
        #pragma unroll
        for (int j = 0; j < 16; ++j)
            c += __popcll(__ballot(ab[j] >= cand));
        if (c >= lvl) thr = cand;
    }
    int cnt = 0;
    #pragma unroll
    for (int j = 0; j < 16; ++j) cnt += __popcll(__ballot(ab[j] >= thr));

    float h[16];
    #pragma unroll
    for (int j = 0; j < 16; ++j) h[j] = b1[lane + 64 * j];

    if (cnt <= PCAP) {
        // compact list; iterate only cnt entries
        int base = 0;
        #pragma unroll
        for (int j = 0; j < 16; ++j) {
            bool keep = ab[j] >= thr;
            unsigned long long m = __ballot(keep);
            if (keep) {
                int pos = base + __popcll(m & ((1ULL << lane) - 1));
                vL[pos] = v[j];
                iLs[pos] = lane + 64 * j;
            }
            base += __popcll(m);
        }
        __builtin_amdgcn_wave_barrier();
        for (int e = 0; e < cnt; ++e) {
            float val = vL[e];
            const float* wr = W1 + (size_t)iLs[e] * CD;
            #pragma unroll
            for (int j = 0; j < 16; ++j)
                h[j] = fmaf(val, wr[lane + 64 * j], h[j]);
        }
    } else {
        // dense fallback: stage pruned row, multiply all CD entries (zeros are no-ops)
        #pragma unroll
        for (int j = 0; j < 16; ++j)
            hS[lane + 64 * j] = (ab[j] >= thr) ? v[j] : 0.f;
        __builtin_amdgcn_wave_barrier();
        for (int e = 0; e < CD; ++e) {
            float val = hS[e];
            const float* wr = W1 + (size_t)e * CD;
            #pragma unroll
            for (int j = 0; j < 16; ++j)
                h[j] = fmaf(val, wr[lane + 64 * j], h[j]);
        }
        __builtin_amdgcn_wave_barrier();
    }

    // relu + stage h for block-wide use
    #pragma unroll
    for (int j = 0; j < 16; ++j) hS[lane + 64 * j] = fmaxf(h[j], 0.f);
    __syncthreads();

    // cooperative W2 pass: wave wv covers i in [wv*256, wv*256+256); each W2 row
    // loaded ONCE per block and applied to all 4 rows (register reuse).
    const float* w2c = W2 + lane;
    float a[4] = {0.f, 0.f, 0.f, 0.f};
    const int i0 = wv * 256;
    #pragma unroll 4
    for (int i = i0; i < i0 + 256; i += 4) {
        float w0 = w2c[(size_t)(i + 0) * PD];
        float w1 = w2c[(size_t)(i + 1) * PD];
        float w2v = w2c[(size_t)(i + 2) * PD];
        float w3 = w2c[(size_t)(i + 3) * PD];
        #pragma unroll
        for (int r = 0; r < 4; ++r) {
            float4 hv = *(const float4*)&hSg[r][i];   // uniform addr -> LDS broadcast
            a[r] = fmaf(hv.x, w0, a[r]);
            a[r] = fmaf(hv.y, w1, a[r]);
            a[r] = fmaf(hv.z, w2v, a[r]);
            a[r] = fmaf(hv.w, w3, a[r]);
        }
    }
    #pragma unroll
    for (int r = 0; r < 4; ++r) prt[wv][r][lane] = a[r];
    __syncthreads();

    float acc = ((prt[0][wv][lane] + prt[1][wv][lane]) +
                 (prt[2][wv][lane] + prt[3][wv][lane])) + b2[lane];
    out[(size_t)perm[slot] * PD + lane] = acc;
}

extern "C" void kernel_launch(void* const* d_in, const int* in_sizes, int n_in,
                              void* d_out, int out_size, void* d_ws, size_t ws_size,
                              hipStream_t stream) {
    const float* x     = (const float*)d_in[0];
    const float* Wq    = (const float*)d_in[1];
    const float* bq    = (const float*)d_in[2];
    const float* keys  = (const float*)d_in[3];
    const float* We    = (const float*)d_in[4];
    const float* S     = (const float*)d_in[5];
    const float* theta = (const float*)d_in[6];
    const float* W1    = (const float*)d_in[7];
    const float* b1    = (const float*)d_in[8];
    const float* W2    = (const float*)d_in[9];
    const float* b2    = (const float*)d_in[10];
    float* out = (float*)d_out;

    const size_t F = (size_t)NB * CD;  // 8.39M elements
    float* Bx = (float*)d_ws;                         // region 0: F floats
    _Float16* zAh = (_Float16*)(Bx + F);              // region 1: 2F halves
    _Float16* zAl = zAh + F;
    float* R1 = (float*)(zAl + F);                    // region 2: F floats, multi-phase
    _Float16* xh  = (_Float16*)R1;
    _Float16* xl  = xh + (size_t)NB * IND;
    _Float16* weh = xl + (size_t)NB * IND;
    _Float16* wel = weh + (size_t)KE * IND * CD;
    _Float16* zBh = (_Float16*)R1;
    _Float16* zBl = zBh + F;
    float* z1 = R1;
    _Float16* sth = (_Float16*)(R1 + F);              // region 3: 2F halves
    _Float16* stl = sth + F;
    float* M  = (float*)(stl + F);
    float* sb = M + IND * KE;
    int* idx     = (int*)(sb + 8);
    int* perm    = idx + NB;
    int* counts  = perm + NB;
    int* offsets = counts + KE;

    // gating first so tsplit can skip unused experts
    k_precompute_M<<<16, 256, 0, stream>>>(Wq, keys, bq, M, sb);
    k_scores<<<NB / 4, 256, 0, stream>>>(x, M, sb, idx);
    k_count<<<1, 256, 0, stream>>>(idx, perm, counts, offsets);

    k_split_rows<<<(NB * IND) / 1024, 256, 0, stream>>>(x, xh, xl, NB * IND);
    {
        dim3 g(IND / 64, CD / 64, KE);
        k_tsplit<<<g, 256, 0, stream>>>(We, weh, wel, IND, counts);
    }
    {
        dim3 g(CD / 64, CD / 64, KE);
        k_tsplit<<<g, 256, 0, stream>>>(S, sth, stl, CD, counts);
    }

    dim3 gg(CD / 128, NB / 128, KE);
    k_mfma<IND, 0><<<gg, 256, 0, stream>>>(xh, xl, weh, wel, theta, nullptr, Bx, zAh, zAl, nullptr, perm, counts, offsets);
    k_mfma<CD, 1><<<gg, 256, 0, stream>>>(zAh, zAl, sth, stl, theta, Bx, nullptr, zBh, zBl, nullptr, perm, counts, offsets);
    k_mfma<CD, 1><<<gg, 256, 0, stream>>>(zBh, zBl, sth, stl, theta, Bx, nullptr, zAh, zAl, nullptr, perm, counts, offsets);
    k_mfma<CD, 1><<<gg, 256, 0, stream>>>(zAh, zAl, sth, stl, theta, Bx, nullptr, zBh, zBl, nullptr, perm, counts, offsets);
    k_mfma<CD, 1><<<gg, 256, 0, stream>>>(zBh, zBl, sth, stl, theta, Bx, nullptr, zAh, zAl, nullptr, perm, counts, offsets);
    k_mfma<CD, 2><<<gg, 256, 0, stream>>>(zAh, zAl, sth, stl, theta, Bx, nullptr, nullptr, nullptr, z1, perm, counts, offsets);

    k_po<<<NB / 4, 256, 0, stream>>>(z1, offsets, W1, b1, W2, b2, perm, out);
}

// Round 6
// 767.360 us; speedup vs baseline: 1.2780x; 1.2780x over previous
//
#include <hip/hip_runtime.h>
#include <math.h>

#define NB 8192
#define IND 512
#define QDIM 128
#define CD 1024
#define KE 8
#define PD 64
#define PCAP 160  // compact-list capacity per row (covers sparsity levels 5,150)

typedef _Float16 h8 __attribute__((ext_vector_type(8)));
typedef _Float16 h4 __attribute__((ext_vector_type(4)));
typedef float fx16 __attribute__((ext_vector_type(16)));

#define GLD16(g, l) __builtin_amdgcn_global_load_lds((const __attribute__((address_space(1))) void*)(g), (__attribute__((address_space(3))) void*)(l), 16, 0, 0)

__device__ __forceinline__ float softt(float v, float th) {
    float a = fabsf(v) - th;
    return a > 0.0f ? copysignf(a, v) : 0.0f;
}

// ---------------- split helpers: v = hi + lo * 2^-11 (lo stored pre-scaled by 2048)
__device__ __forceinline__ void fsplit(float v, _Float16& hi, _Float16& lo) {
    hi = (_Float16)v;
    lo = (_Float16)((v - (float)hi) * 2048.0f);
}

// ---------------- K0: M = Wq @ keys^T / sqrt(QDIM), sb = bq @ keys^T / sqrt(QDIM)
__global__ void k_precompute_M(const float* __restrict__ Wq, const float* __restrict__ keys,
                               const float* __restrict__ bq, float* __restrict__ M,
                               float* __restrict__ sb) {
    const float RSQ = 0.088388347648318447f; // 1/sqrt(128)
    int g = blockIdx.x * 256 + threadIdx.x;  // 0..4095
    if (g < IND * KE) {
        int i = g >> 3, k = g & 7;
        float s = 0.f;
        for (int q = 0; q < QDIM; ++q) s += Wq[i * QDIM + q] * keys[k * QDIM + q];
        M[g] = s * RSQ;  // M[i*8+k]
    }
    if (blockIdx.x == 0 && threadIdx.x < KE) {
        int k = threadIdx.x;
        float s = 0.f;
        for (int q = 0; q < QDIM; ++q) s += bq[q] * keys[k * QDIM + q];
        sb[k] = s * RSQ;
    }
}

// ---------------- K1: per-row scores -> expert idx (one wave per row, no atomics)
__global__ __launch_bounds__(256)
void k_scores(const float* __restrict__ x, const float* __restrict__ M,
              const float* __restrict__ sb, int* __restrict__ idx) {
    __shared__ float Ms[KE][IND];
    __shared__ float sbs[KE];
    int t = threadIdx.x;
    #pragma unroll
    for (int j = 0; j < 16; ++j) {
        int e = j * 256 + t;
        Ms[e & 7][e >> 3] = M[e];
    }
    if (t < KE) sbs[t] = sb[t];
    __syncthreads();
    int w = t >> 6, lane = t & 63;
    int row = blockIdx.x * 4 + w;
    const float* xr = x + (size_t)row * IND;
    float sc[KE];
    #pragma unroll
    for (int k = 0; k < KE; ++k) sc[k] = 0.f;
    #pragma unroll
    for (int j = 0; j < IND / 64; ++j) {
        int ii = lane + 64 * j;
        float xv = xr[ii];
        #pragma unroll
        for (int k = 0; k < KE; ++k) sc[k] += xv * Ms[k][ii];
    }
    #pragma unroll
    for (int k = 0; k < KE; ++k) {
        #pragma unroll
        for (int off = 32; off >= 1; off >>= 1) sc[k] += __shfl_down(sc[k], off, 64);
    }
    if (lane == 0) {
        float smax = -1e30f;
        #pragma unroll
        for (int k = 0; k < KE; ++k) { sc[k] += sbs[k]; smax = fmaxf(smax, sc[k]); }
        const float LN09 = -0.105360515657826301f;  // ln(0.9)
        int e = 0;
        #pragma unroll
        for (int k = KE - 1; k >= 0; --k)
            if (sc[k] >= smax + LN09) e = k;  // smallest eligible k (sl is increasing)
        idx[row] = e;
    }
}

// ---------------- K2: single-block counting sort: counts, offsets, perm (no global atomics)
__global__ __launch_bounds__(256)
void k_count(const int* __restrict__ idx, int* __restrict__ perm,
             int* __restrict__ counts, int* __restrict__ offsets) {
    __shared__ int hist[256][KE];      // 8 KB
    __shared__ int sc[2][KE][256];     // 16 KB ping-pong scan
    __shared__ int base[KE];
    const int t = threadIdx.x;
    int pc[KE];
    #pragma unroll
    for (int e = 0; e < KE; ++e) pc[e] = 0;
    for (int j = 0; j < NB / 256; ++j) pc[idx[j * 256 + t]]++;
    #pragma unroll
    for (int e = 0; e < KE; ++e) { hist[t][e] = pc[e]; sc[0][e][t] = pc[e]; }
    __syncthreads();
    int cur = 0;
    for (int d = 1; d < 256; d <<= 1) {
        #pragma unroll
        for (int e = 0; e < KE; ++e) {
            int v = sc[cur][e][t];
            if (t >= d) v += sc[cur][e][t - d];
            sc[cur ^ 1][e][t] = v;
        }
        cur ^= 1;
        __syncthreads();
    }
    if (t == 0) {
        int a = 0;
        #pragma unroll
        for (int e = 0; e < KE; ++e) {
            int tot = sc[cur][e][255];
            base[e] = a; offsets[e] = a; counts[e] = tot; a += tot;
        }
    }
    __syncthreads();
    int pos[KE];
    #pragma unroll
    for (int e = 0; e < KE; ++e) pos[e] = base[e] + sc[cur][e][t] - hist[t][e];
    for (int j = 0; j < NB / 256; ++j) {
        int r = j * 256 + t;
        int e = idx[r];
        perm[pos[e]++] = r;
    }
}

// ---------------- K4: elementwise split of x into INTERLEAVED hi/lo fp16 planes.
// [R6] Layout [row][kg][hi8|lo8]: each 16-k group of a row = 32 contiguous halves
// (64B) — keeps per-iter staging reads full-cache-line at BK=16.
__global__ __launch_bounds__(256)
void k_split_rows(const float* __restrict__ src, _Float16* __restrict__ dst, int n) {
    int i = (blockIdx.x * 256 + threadIdx.x) * 8;
    if (i < n) {
        float4 v0 = *(const float4*)(src + i);
        float4 v1 = *(const float4*)(src + i + 4);
        h8 hh, ll;
        #pragma unroll
        for (int j = 0; j < 4; ++j) {
            _Float16 a, b;
            fsplit((&v0.x)[j], a, b);
            hh[j] = a; ll[j] = b;
            fsplit((&v1.x)[j], a, b);
            hh[4 + j] = a; ll[4 + j] = b;
        }
        *(h8*)(dst + 2 * (size_t)i) = hh;
        *(h8*)(dst + 2 * (size_t)i + 8) = ll;
    }
}

// ---------------- K5: transpose+split: src[e][K][CD] fp32 -> tI[e][CD][2K] fp16
// interleaved [col][kg][hi8|lo8]. Skips experts with zero selected rows.
__global__ __launch_bounds__(256)
void k_tsplit(const float* __restrict__ src, _Float16* __restrict__ tI,
              int K, const int* __restrict__ counts) {
    int e = blockIdx.z;
    if (counts[e] == 0) return;  // expert never used downstream
    __shared__ float tile[64][65];
    int k0 = blockIdx.x * 64;
    int n0 = blockIdx.y * 64;
    const float* s = src + (size_t)e * K * CD;
    int t = threadIdx.x;
    int tr = t >> 4;
    int tc = (t & 15) * 4;
    #pragma unroll
    for (int p = 0; p < 4; ++p) {
        int kk = tr + p * 16;
        float4 v = *(const float4*)&s[(size_t)(k0 + kk) * CD + n0 + tc];
        #pragma unroll
        for (int j = 0; j < 4; ++j) tile[kk][tc + j] = (&v.x)[j];
    }
    __syncthreads();
    int n = t >> 2;
    int kq = (t & 3) * 16;
    h8 hh0, hh1, ll0, ll1;
    #pragma unroll
    for (int j = 0; j < 8; ++j) {
        _Float16 a, b;
        fsplit(tile[kq + j][n], a, b);
        hh0[j] = a; ll0[j] = b;
        fsplit(tile[kq + 8 + j][n], a, b);
        hh1[j] = a; ll1[j] = b;
    }
    size_t ob = ((size_t)e * CD + n0 + n) * (size_t)(2 * K) + (size_t)(k0 + kq) * 2;
    *(h8*)(tI + ob) = hh0;
    *(h8*)(tI + ob + 8) = ll0;
    *(h8*)(tI + ob + 16) = hh1;
    *(h8*)(tI + ob + 24) = ll1;
}

// ---------------- grouped split-fp16 MFMA GEMM — 64x64 tile, ONE WAVE per block.
// [R5 post-mortem] LDS-free direct loads: 2x L2 traffic (no reuse) + 32B strided
// segments -> 157us. REVERTED. [R4] counted-vmcnt at 128² was 80us but grid-locked
// at 2 blocks/CU with 4-wave lockstep barriers.
// [R6] 2048 single-wave blocks = 8 INDEPENDENT waves/CU, ZERO barriers (single-wave
// workgroup needs no __syncthreads): per-wave counted-vmcnt pipeline
//   ds_read(buf) -> lgkmcnt(0) -> restage kt+2 into freed buf -> setprio(1) MFMA
//   setprio(0) -> vmcnt(8)   [vmcnt(0) only at tail]
// LDS 16KB/block x8 = 128KB/CU. Interleaved planes keep staging 64B/row/iter
// (full-line). Slot map lc=2*kg+comp identical to prior swizzle (&3), read-side
// unchanged; bank spread re-derived conflict-free (4 lanes/slot-group balanced).
// Single accumulator via exact 2^-11 operand pre-scale (R3, absmax-verified).
template <int KDIM, int MODE>
__global__ __launch_bounds__(64, 2)
void k_mfma(const _Float16* __restrict__ AI, const _Float16* __restrict__ BI,
            const float* __restrict__ theta, const float* __restrict__ BxBuf,
            float* __restrict__ BxOut, _Float16* __restrict__ zI,
            float* __restrict__ zf,
            const int* __restrict__ perm, const int* __restrict__ counts,
            const int* __restrict__ offsets) {
    const int e = blockIdx.z;
    const int cnt = counts[e];
    const int p = blockIdx.x + 16 * blockIdx.y;   // 0..2047
    const int gx = p & 7;                          // XCD id (round-robin dispatch)
    const int qq = p >> 3;                         // 0..255
    const int bxl = qq & 15;                       // n-tile 0..15
    const int byl = gx + 8 * (qq >> 4);            // m-tile 0..127 (contig stripe/XCD)
    const int m0 = byl * 64;
    if (m0 >= cnt) return;
    const int n0 = bxl * 64;
    const int off = offsets[e];
    const float th = theta[e];

    __shared__ _Float16 Asl[2][64 * 32];  // 4 KB per buffer
    __shared__ _Float16 Bsl[2][64 * 32];

    const int lane = threadIdx.x;          // 0..63
    const int q = lane >> 5;
    const int ml = lane & 31;

    // staging source pointers: chunk i covers rows i*16..i*16+15, 4 lanes/row,
    // lane's 16B = slot lc (kg=lc>>1, comp=lc&1) of the row's 64B k-group
    const _Float16* aptr[4];
    const _Float16* bptr[4];
    #pragma unroll
    for (int i = 0; i < 4; ++i) {
        int r = i * 16 + (lane >> 2);
        int pc = lane & 3;
        int lc = pc ^ ((r ^ (r >> 3)) & 3);
        int mrow = m0 + r; if (mrow > cnt - 1) mrow = cnt - 1;
        size_t grow;
        if constexpr (MODE == 0) grow = (size_t)perm[off + mrow];
        else grow = (size_t)(off + mrow);
        aptr[i] = AI + grow * (size_t)(2 * KDIM) + lc * 8;
        bptr[i] = BI + ((size_t)e * CD + n0 + r) * (size_t)(2 * KDIM) + lc * 8;
    }

    fx16 acc[2][2];
    #pragma unroll
    for (int mt = 0; mt < 2; ++mt)
        #pragma unroll
        for (int nt = 0; nt < 2; ++nt)
            #pragma unroll
            for (int g = 0; g < 16; ++g) acc[mt][nt][g] = 0.f;

    auto stage = [&](int kt, int buf) {
        const int koff = kt * 32;  // 32 halves per row per 16-k tile
        #pragma unroll
        for (int i = 0; i < 4; ++i) {
            GLD16(aptr[i] + koff, &Asl[buf][i * 512]);
            GLD16(bptr[i] + koff, &Bsl[buf][i * 512]);
        }
    };

    const _Float16 SC = (_Float16)4.8828125e-4f;  // 2^-11, exact exponent shift

    const int NT = KDIM / 16;
    stage(0, 0);
    stage(1, 1);
    asm volatile("s_waitcnt vmcnt(8)" ::: "memory");  // stage(0) complete
    __builtin_amdgcn_sched_barrier(0);

    for (int kt = 0; kt < NT; ++kt) {
        const int buf = kt & 1;
        const int base = q * 2;
        h8 ah[2], al2[2], bh2[2], bl2[2];
        #pragma unroll
        for (int mt = 0; mt < 2; ++mt) {
            int row = mt * 32 + ml;
            int sw = (row ^ (row >> 3)) & 3;
            int mb = row * 32;
            ah[mt]  = *(const h8*)&Asl[buf][mb + (((base + 0) ^ sw) * 8)];
            al2[mt] = *(const h8*)&Asl[buf][mb + (((base + 1) ^ sw) * 8)];
        }
        #pragma unroll
        for (int nt = 0; nt < 2; ++nt) {
            int col = nt * 32 + ml;
            int sw = (col ^ (col >> 3)) & 3;
            int nb = col * 32;
            bh2[nt] = *(const h8*)&Bsl[buf][nb + (((base + 0) ^ sw) * 8)];
            bl2[nt] = *(const h8*)&Bsl[buf][nb + (((base + 1) ^ sw) * 8)];
        }
        asm volatile("s_waitcnt lgkmcnt(0)" ::: "memory");  // my reads retired
        __builtin_amdgcn_sched_barrier(0);
        if (kt + 2 < NT) stage(kt + 2, buf);  // refill freed buf; flies during MFMA
        __builtin_amdgcn_s_setprio(1);
        h8 ahs[2], bhs[2];
        #pragma unroll
        for (int mt = 0; mt < 2; ++mt) ahs[mt] = ah[mt] * SC;
        #pragma unroll
        for (int nt = 0; nt < 2; ++nt) bhs[nt] = bh2[nt] * SC;
        #pragma unroll
        for (int mt = 0; mt < 2; ++mt)
            #pragma unroll
            for (int nt = 0; nt < 2; ++nt) {
                acc[mt][nt] = __builtin_amdgcn_mfma_f32_32x32x16_f16(ah[mt],  bh2[nt], acc[mt][nt], 0, 0, 0);
                acc[mt][nt] = __builtin_amdgcn_mfma_f32_32x32x16_f16(ahs[mt], bl2[nt], acc[mt][nt], 0, 0, 0);
                acc[mt][nt] = __builtin_amdgcn_mfma_f32_32x32x16_f16(al2[mt], bhs[nt], acc[mt][nt], 0, 0, 0);
            }
        __builtin_amdgcn_s_setprio(0);
        if (kt + 1 < NT) {
            if (kt + 2 < NT) {
                asm volatile("s_waitcnt vmcnt(8)" ::: "memory");  // kt+1's 8 done
            } else {
                asm volatile("s_waitcnt vmcnt(0)" ::: "memory");  // tail drain
            }
            __builtin_amdgcn_sched_barrier(0);
        }
    }

    // epilogue: C/D layout col=lane&31, row=(g&3)+8*(g>>2)+4*q  [m74/m101]
    #pragma unroll
    for (int mt = 0; mt < 2; ++mt)
        #pragma unroll
        for (int nt = 0; nt < 2; ++nt) {
            #pragma unroll
            for (int g = 0; g < 16; ++g) {
                int rl = mt * 32 + (g & 3) + 8 * (g >> 2) + 4 * q;
                int mrow = m0 + rl;
                if (mrow < cnt) {
                    int col = n0 + nt * 32 + ml;
                    size_t addr = (size_t)(off + mrow) * CD + col;
                    float v = acc[mt][nt][g];
                    if constexpr (MODE == 0) {
                        BxOut[addr] = v;
                        float z = softt(v, th);
                        _Float16 a, b;
                        fsplit(z, a, b);
                        size_t zb = (size_t)(off + mrow) * (2 * CD) + (size_t)(col >> 3) * 16 + (col & 7);
                        zI[zb] = a; zI[zb + 8] = b;
                    } else if constexpr (MODE == 1) {
                        float z = softt(v + BxBuf[addr], th);
                        _Float16 a, b;
                        fsplit(z, a, b);
                        size_t zb = (size_t)(off + mrow) * (2 * CD) + (size_t)(col >> 3) * 16 + (col & 7);
                        zI[zb] = a; zI[zb + 8] = b;
                    } else {
                        zf[addr] = softt(v + BxBuf[addr], th);
                    }
                }
            }
        }
}

// ---------------- K6+K7 fused: per-wave top-k prune + h = b1 + sparse_z@W1, then
// BLOCK-COOPERATIVE out = relu(h)@W2 + b2. [R1: 4x W2 L2-traffic reduction]
__global__ __launch_bounds__(256)
void k_po(const float* __restrict__ z, const int* __restrict__ offsets,
          const float* __restrict__ W1, const float* __restrict__ b1,
          const float* __restrict__ W2, const float* __restrict__ b2,
          const int* __restrict__ perm, float* __restrict__ out) {
    const int SL[KE] = {5, 150, 296, 441, 587, 732, 878, 1024};
    __shared__ float vLg[4][PCAP];   // 2.5 KB
    __shared__ int   iLg[4][PCAP];   // 2.5 KB
    __shared__ float hSg[4][CD];     // 16 KB; doubles as dense pruned-z staging
    __shared__ float prt[4][4][64];  // 4 KB [wave][row][lane] partial sums
    const int t = threadIdx.x;
    const int lane = t & 63;
    const int wv = t >> 6;
    const int slot = blockIdx.x * 4 + wv;
    float* vL = vLg[wv];
    int* iLs = iLg[wv];
    float* hS = hSg[wv];

    int k = 0;
    #pragma unroll
    for (int e = 1; e < KE; ++e)
        if (slot >= offsets[e]) k = e;
    const int lvl = SL[k];

    const float* zr = z + (size_t)slot * CD;
    float v[16];
    unsigned ab[16];
    #pragma unroll
    for (int j = 0; j < 16; ++j) {
        v[j] = zr[lane + 64 * j];
        ab[j] = __float_as_uint(fabsf(v[j]));
    }
    // exact kth-largest |z| bit pattern; count via ballot+popc (no shuffles)
    unsigned thr = 0;
    for (int b = 30; b >= 0; --b) {
        unsigned cand = thr | (1u << b);
        int c = 0;
        #pragma unroll
        for (int j = 0; j < 16; ++j)
            c += __popcll(__ballot(ab[j] >= cand));
        if (c >= lvl) thr = cand;
    }
    int cnt = 0;
    #pragma unroll
    for (int j = 0; j < 16; ++j) cnt += __popcll(__ballot(ab[j] >= thr));

    float h[16];
    #pragma unroll
    for (int j = 0; j < 16; ++j) h[j] = b1[lane + 64 * j];

    if (cnt <= PCAP) {
        // compact list; iterate only cnt entries
        int base = 0;
        #pragma unroll
        for (int j = 0; j < 16; ++j) {
            bool keep = ab[j] >= thr;
            unsigned long long m = __ballot(keep);
            if (keep) {
                int pos = base + __popcll(m & ((1ULL << lane) - 1));
                vL[pos] = v[j];
                iLs[pos] = lane + 64 * j;
            }
            base += __popcll(m);
        }
        __builtin_amdgcn_wave_barrier();
        for (int e = 0; e < cnt; ++e) {
            float val = vL[e];
            const float* wr = W1 + (size_t)iLs[e] * CD;
            #pragma unroll
            for (int j = 0; j < 16; ++j)
                h[j] = fmaf(val, wr[lane + 64 * j], h[j]);
        }
    } else {
        // dense fallback: stage pruned row, multiply all CD entries (zeros are no-ops)
        #pragma unroll
        for (int j = 0; j < 16; ++j)
            hS[lane + 64 * j] = (ab[j] >= thr) ? v[j] : 0.f;
        __builtin_amdgcn_wave_barrier();
        for (int e = 0; e < CD; ++e) {
            float val = hS[e];
            const float* wr = W1 + (size_t)e * CD;
            #pragma unroll
            for (int j = 0; j < 16; ++j)
                h[j] = fmaf(val, wr[lane + 64 * j], h[j]);
        }
        __builtin_amdgcn_wave_barrier();
    }

    // relu + stage h for block-wide use
    #pragma unroll
    for (int j = 0; j < 16; ++j) hSg[wv][lane + 64 * j] = fmaxf(h[j], 0.f);
    __syncthreads();

    // cooperative W2 pass: wave wv covers i in [wv*256, wv*256+256); each W2 row
    // loaded ONCE per block and applied to all 4 rows (register reuse).
    const float* w2c = W2 + lane;
    float a[4] = {0.f, 0.f, 0.f, 0.f};
    const int i0 = wv * 256;
    #pragma unroll 4
    for (int i = i0; i < i0 + 256; i += 4) {
        float w0 = w2c[(size_t)(i + 0) * PD];
        float w1 = w2c[(size_t)(i + 1) * PD];
        float w2v = w2c[(size_t)(i + 2) * PD];
        float w3 = w2c[(size_t)(i + 3) * PD];
        #pragma unroll
        for (int r = 0; r < 4; ++r) {
            float4 hv = *(const float4*)&hSg[r][i];   // uniform addr -> LDS broadcast
            a[r] = fmaf(hv.x, w0, a[r]);
            a[r] = fmaf(hv.y, w1, a[r]);
            a[r] = fmaf(hv.z, w2v, a[r]);
            a[r] = fmaf(hv.w, w3, a[r]);
        }
    }
    #pragma unroll
    for (int r = 0; r < 4; ++r) prt[wv][r][lane] = a[r];
    __syncthreads();

    float acc = ((prt[0][wv][lane] + prt[1][wv][lane]) +
                 (prt[2][wv][lane] + prt[3][wv][lane])) + b2[lane];
    out[(size_t)perm[slot] * PD + lane] = acc;
}

extern "C" void kernel_launch(void* const* d_in, const int* in_sizes, int n_in,
                              void* d_out, int out_size, void* d_ws, size_t ws_size,
                              hipStream_t stream) {
    const float* x     = (const float*)d_in[0];
    const float* Wq    = (const float*)d_in[1];
    const float* bq    = (const float*)d_in[2];
    const float* keys  = (const float*)d_in[3];
    const float* We    = (const float*)d_in[4];
    const float* S     = (const float*)d_in[5];
    const float* theta = (const float*)d_in[6];
    const float* W1    = (const float*)d_in[7];
    const float* b1    = (const float*)d_in[8];
    const float* W2    = (const float*)d_in[9];
    const float* b2    = (const float*)d_in[10];
    float* out = (float*)d_out;

    const size_t F = (size_t)NB * CD;  // 8.39M elements
    float* Bx = (float*)d_ws;                         // region 0: F floats
    _Float16* zA = (_Float16*)(Bx + F);               // region 1: 2F halves (interleaved)
    float* R1 = (float*)(zA + 2 * F);                 // region 2: F floats, multi-phase
    _Float16* xI  = (_Float16*)R1;                    //   NB*IND*2 halves
    _Float16* weI = xI + (size_t)NB * IND * 2;        //   KE*IND*CD*2 halves (sums to F floats)
    _Float16* zB  = (_Float16*)R1;                    //   2F halves (later phase)
    float* z1 = R1;                                   //   F floats (final phase)
    _Float16* stI = (_Float16*)(R1 + F);              // region 3: 2F halves (interleaved S^T)
    float* M  = (float*)(stI + 2 * F);
    float* sb = M + IND * KE;
    int* idx     = (int*)(sb + 8);
    int* perm    = idx + NB;
    int* counts  = perm + NB;
    int* offsets = counts + KE;

    // gating first so tsplit can skip unused experts
    k_precompute_M<<<16, 256, 0, stream>>>(Wq, keys, bq, M, sb);
    k_scores<<<NB / 4, 256, 0, stream>>>(x, M, sb, idx);
    k_count<<<1, 256, 0, stream>>>(idx, perm, counts, offsets);

    k_split_rows<<<(NB * IND) / (8 * 256), 256, 0, stream>>>(x, xI, NB * IND);
    {
        dim3 g(IND / 64, CD / 64, KE);
        k_tsplit<<<g, 256, 0, stream>>>(We, weI, IND, counts);
    }
    {
        dim3 g(CD / 64, CD / 64, KE);
        k_tsplit<<<g, 256, 0, stream>>>(S, stI, CD, counts);
    }

    dim3 gg(CD / 64, NB / 64, KE);  // (16, 128, 8) — 2048 single-wave blocks
    k_mfma<IND, 0><<<gg, 64, 0, stream>>>(xI, weI, theta, nullptr, Bx, zA, nullptr, perm, counts, offsets);
    k_mfma<CD, 1><<<gg, 64, 0, stream>>>(zA, stI, theta, Bx, nullptr, zB, nullptr, perm, counts, offsets);
    k_mfma<CD, 1><<<gg, 64, 0, stream>>>(zB, stI, theta, Bx, nullptr, zA, nullptr, perm, counts, offsets);
    k_mfma<CD, 1><<<gg, 64, 0, stream>>>(zA, stI, theta, Bx, nullptr, zB, nullptr, perm, counts, offsets);
    k_mfma<CD, 1><<<gg, 64, 0, stream>>>(zB, stI, theta, Bx, nullptr, zA, nullptr, perm, counts, offsets);
    k_mfma<CD, 2><<<gg, 64, 0, stream>>>(zA, stI, theta, Bx, nullptr, nullptr, z1, perm, counts, offsets);

    k_po<<<NB / 4, 256, 0, stream>>>(z1, offsets, W1, b1, W2, b2, perm, out);
}

// Round 9
// 604.810 us; speedup vs baseline: 1.6215x; 1.2688x over previous
//
#include <hip/hip_runtime.h>
#include <math.h>

#define NB 8192
#define IND 512
#define QDIM 128
#define CD 1024
#define KE 8
#define PD 64
#define PCAP 160  // compact-list capacity per row (covers sparsity levels 5,150)

typedef _Float16 h8 __attribute__((ext_vector_type(8)));
typedef _Float16 h4 __attribute__((ext_vector_type(4)));
typedef float fx16 __attribute__((ext_vector_type(16)));

#define GLD16(g, l) __builtin_amdgcn_global_load_lds((const __attribute__((address_space(1))) void*)(g), (__attribute__((address_space(3))) void*)(l), 16, 0, 0)

__device__ __forceinline__ float softt(float v, float th) {
    float a = fabsf(v) - th;
    return a > 0.0f ? copysignf(a, v) : 0.0f;
}

// ---------------- split helpers: v = hi + lo * 2^-11 (lo stored pre-scaled by 2048)
// [R7 lesson] BOTH GEMM operands must keep the full hi/lo split: single-fp16 B gave
// z-error ~1e-3 which flipped top-k selection in ~hundreds of rows (5th/6th |z| gap
// ~0.03) -> absmax 0.069 FAIL. Split (rel err 2^-22) keeps selection exact.
__device__ __forceinline__ void fsplit(float v, _Float16& hi, _Float16& lo) {
    hi = (_Float16)v;
    lo = (_Float16)((v - (float)hi) * 2048.0f);
}

// ---------------- K0: M = Wq @ keys^T / sqrt(QDIM), sb = bq @ keys^T / sqrt(QDIM)
__global__ void k_precompute_M(const float* __restrict__ Wq, const float* __restrict__ keys,
                               const float* __restrict__ bq, float* __restrict__ M,
                               float* __restrict__ sb) {
    const float RSQ = 0.088388347648318447f; // 1/sqrt(128)
    int g = blockIdx.x * 256 + threadIdx.x;  // 0..4095
    if (g < IND * KE) {
        int i = g >> 3, k = g & 7;
        float s = 0.f;
        for (int q = 0; q < QDIM; ++q) s += Wq[i * QDIM + q] * keys[k * QDIM + q];
        M[g] = s * RSQ;  // M[i*8+k]
    }
    if (blockIdx.x == 0 && threadIdx.x < KE) {
        int k = threadIdx.x;
        float s = 0.f;
        for (int q = 0; q < QDIM; ++q) s += bq[q] * keys[k * QDIM + q];
        sb[k] = s * RSQ;
    }
}

// ---------------- K1: per-row scores -> expert idx (one wave per row, no atomics)
__global__ __launch_bounds__(256)
void k_scores(const float* __restrict__ x, const float* __restrict__ M,
              const float* __restrict__ sb, int* __restrict__ idx) {
    __shared__ float Ms[KE][IND];
    __shared__ float sbs[KE];
    int t = threadIdx.x;
    #pragma unroll
    for (int j = 0; j < 16; ++j) {
        int e = j * 256 + t;
        Ms[e & 7][e >> 3] = M[e];
    }
    if (t < KE) sbs[t] = sb[t];
    __syncthreads();
    int w = t >> 6, lane = t & 63;
    int row = blockIdx.x * 4 + w;
    const float* xr = x + (size_t)row * IND;
    float sc[KE];
    #pragma unroll
    for (int k = 0; k < KE; ++k) sc[k] = 0.f;
    #pragma unroll
    for (int j = 0; j < IND / 64; ++j) {
        int ii = lane + 64 * j;
        float xv = xr[ii];
        #pragma unroll
        for (int k = 0; k < KE; ++k) sc[k] += xv * Ms[k][ii];
    }
    #pragma unroll
    for (int k = 0; k < KE; ++k) {
        #pragma unroll
        for (int off = 32; off >= 1; off >>= 1) sc[k] += __shfl_down(sc[k], off, 64);
    }
    if (lane == 0) {
        float smax = -1e30f;
        #pragma unroll
        for (int k = 0; k < KE; ++k) { sc[k] += sbs[k]; smax = fmaxf(smax, sc[k]); }
        const float LN09 = -0.105360515657826301f;  // ln(0.9)
        int e = 0;
        #pragma unroll
        for (int k = KE - 1; k >= 0; --k)
            if (sc[k] >= smax + LN09) e = k;  // smallest eligible k (sl is increasing)
        idx[row] = e;
    }
}

// ---------------- K2: single-block counting sort: counts, offsets, perm (no global atomics)
__global__ __launch_bounds__(256)
void k_count(const int* __restrict__ idx, int* __restrict__ perm,
             int* __restrict__ counts, int* __restrict__ offsets) {
    __shared__ int hist[256][KE];      // 8 KB
    __shared__ int sc[2][KE][256];     // 16 KB ping-pong scan
    __shared__ int base[KE];
    const int t = threadIdx.x;
    int pc[KE];
    #pragma unroll
    for (int e = 0; e < KE; ++e) pc[e] = 0;
    for (int j = 0; j < NB / 256; ++j) pc[idx[j * 256 + t]]++;
    #pragma unroll
    for (int e = 0; e < KE; ++e) { hist[t][e] = pc[e]; sc[0][e][t] = pc[e]; }
    __syncthreads();
    int cur = 0;
    for (int d = 1; d < 256; d <<= 1) {
        #pragma unroll
        for (int e = 0; e < KE; ++e) {
            int v = sc[cur][e][t];
            if (t >= d) v += sc[cur][e][t - d];
            sc[cur ^ 1][e][t] = v;
        }
        cur ^= 1;
        __syncthreads();
    }
    if (t == 0) {
        int a = 0;
        #pragma unroll
        for (int e = 0; e < KE; ++e) {
            int tot = sc[cur][e][255];
            base[e] = a; offsets[e] = a; counts[e] = tot; a += tot;
        }
    }
    __syncthreads();
    int pos[KE];
    #pragma unroll
    for (int e = 0; e < KE; ++e) pos[e] = base[e] + sc[cur][e][t] - hist[t][e];
    for (int j = 0; j < NB / 256; ++j) {
        int r = j * 256 + t;
        int e = idx[r];
        perm[pos[e]++] = r;
    }
}

// ---------------- K4: elementwise split of x into hi/lo fp16 planes
__global__ __launch_bounds__(256)
void k_split_rows(const float* __restrict__ src, _Float16* __restrict__ ph,
                  _Float16* __restrict__ pl, int n) {
    int i = (blockIdx.x * 256 + threadIdx.x) * 4;
    if (i < n) {
        float4 v = *(const float4*)(src + i);
        h4 hh, ll;
        #pragma unroll
        for (int j = 0; j < 4; ++j) {
            _Float16 a, b;
            fsplit((&v.x)[j], a, b);
            hh[j] = a; ll[j] = b;
        }
        *(h4*)(ph + i) = hh;
        *(h4*)(pl + i) = ll;
    }
}

// ---------------- K5: transpose+split: src[e][K][CD] fp32 -> th/tl[e][CD][K] fp16
// Skips experts with zero selected rows (counts from k_count — launch-ordered before).
__global__ __launch_bounds__(256)
void k_tsplit(const float* __restrict__ src, _Float16* __restrict__ th,
              _Float16* __restrict__ tl, int K, const int* __restrict__ counts) {
    int e = blockIdx.z;
    if (counts[e] == 0) return;  // expert never used downstream
    __shared__ float tile[64][65];
    int k0 = blockIdx.x * 64;
    int n0 = blockIdx.y * 64;
    const float* s = src + (size_t)e * K * CD;
    int t = threadIdx.x;
    int tr = t >> 4;
    int tc = (t & 15) * 4;
    #pragma unroll
    for (int p = 0; p < 4; ++p) {
        int kk = tr + p * 16;
        float4 v = *(const float4*)&s[(size_t)(k0 + kk) * CD + n0 + tc];
        #pragma unroll
        for (int j = 0; j < 4; ++j) tile[kk][tc + j] = (&v.x)[j];
    }
    __syncthreads();
    int n = t >> 2;
    int kq = (t & 3) * 16;
    h8 hh0, hh1, ll0, ll1;
    #pragma unroll
    for (int j = 0; j < 8; ++j) {
        _Float16 a, b;
        fsplit(tile[kq + j][n], a, b);
        hh0[j] = a; ll0[j] = b;
        fsplit(tile[kq + 8 + j][n], a, b);
        hh1[j] = a; ll1[j] = b;
    }
    size_t ob = ((size_t)e * CD + n0 + n) * K + k0 + kq;
    *(h8*)(th + ob) = hh0;
    *(h8*)(th + ob + 8) = hh1;
    *(h8*)(tl + ob) = ll0;
    *(h8*)(tl + ob + 8) = ll1;
}

// ---------------- grouped split-fp16 MFMA GEMM, 128x128 tile, BK=32 [R4 — verified 80us].
// Counted-vmcnt pipeline (T4): 2-deep prefetch, per iter:
//   ds_reads -> lgkmcnt(0) -> s_barrier -> stage(kt+2) into freed buf
//   -> MFMAs -> vmcnt(8) [never 0 until tail] -> s_barrier
// sched_barrier(0) after each asm wait (rule #18). Single accumulator via exact
// 2^-11 operand pre-scale. Bank swizzle g(r)=(r^(r>>3))&7, 0 conflicts measured.
// [R5/R6/R7 post-mortems] LDS-free direct loads: -2x (lost coalescing+reuse);
// 64² tile: -1.5x (A-refetch + latency-naked 1-wave blocks); B single-fp16:
// FAIL (top-k selection flips). This structure + full split is the keeper.
template <int KDIM, int MODE>
__global__ __launch_bounds__(256, 2)
void k_mfma(const _Float16* __restrict__ Ah, const _Float16* __restrict__ Al,
            const _Float16* __restrict__ Bh, const _Float16* __restrict__ Bl,
            const float* __restrict__ theta, const float* __restrict__ BxBuf,
            float* __restrict__ BxOut, _Float16* __restrict__ zh, _Float16* __restrict__ zl,
            float* __restrict__ zf,
            const int* __restrict__ perm, const int* __restrict__ counts,
            const int* __restrict__ offsets) {
    const int e = blockIdx.z;
    const int cnt = counts[e];
    const int p = blockIdx.x + 8 * blockIdx.y;
    const int gx = p & 7;
    const int qq = p >> 3;
    const int bxl = qq & 7;
    const int byl = gx + 8 * (qq >> 3);
    const int m0 = byl * 128;
    if (m0 >= cnt) return;
    const int n0 = bxl * 128;
    const int off = offsets[e];
    const float th = theta[e];

    __shared__ _Float16 Asl[2][128 * 64];  // 16 KB per buffer
    __shared__ _Float16 Bsl[2][128 * 64];

    const int t = threadIdx.x;
    const int lane = t & 63;
    const int w = t >> 6;

    const _Float16* aptr[4];
    const _Float16* bptr[4];
    #pragma unroll
    for (int i = 0; i < 4; ++i) {
        int s = w * 4 + i;
        int r = s * 8 + (lane >> 3);
        int pc = lane & 7;
        int lc = pc ^ ((r ^ (r >> 3)) & 7);
        int comp = lc & 1;
        int kg = lc >> 1;
        int mrow = m0 + r; if (mrow > cnt - 1) mrow = cnt - 1;
        size_t grow;
        if constexpr (MODE == 0) grow = (size_t)perm[off + mrow];
        else grow = (size_t)(off + mrow);
        aptr[i] = (comp ? Al : Ah) + grow * KDIM + kg * 8;
        bptr[i] = (comp ? Bl : Bh) + ((size_t)e * CD + n0 + r) * KDIM + kg * 8;
    }

    const int wm = w >> 1, wn = w & 1;
    const int q = lane >> 5;
    const int ml = lane & 31;

    fx16 acc[2][2];
    #pragma unroll
    for (int mt = 0; mt < 2; ++mt)
        #pragma unroll
        for (int nt = 0; nt < 2; ++nt)
            #pragma unroll
            for (int g = 0; g < 16; ++g) acc[mt][nt][g] = 0.f;

    auto stage = [&](int kt, int buf) {
        const int koff = kt * 32;
        #pragma unroll
        for (int i = 0; i < 4; ++i) {
            GLD16(aptr[i] + koff, &Asl[buf][(w * 4 + i) * 512]);
            GLD16(bptr[i] + koff, &Bsl[buf][(w * 4 + i) * 512]);
        }
    };

    const _Float16 SC = (_Float16)4.8828125e-4f;  // 2^-11, exact exponent shift

    const int NT = KDIM / 32;
    stage(0, 0);
    stage(1, 1);
    asm volatile("s_waitcnt vmcnt(8)" ::: "memory");
    __builtin_amdgcn_sched_barrier(0);
    __builtin_amdgcn_s_barrier();

    for (int kt = 0; kt < NT; ++kt) {
        const int buf = kt & 1;
        // ---- phase A: LDS -> registers (both k-slices)
        h8 ah[2][2], al2[2][2], bh2[2][2], bl2[2][2];  // [ks][mt/nt]
        #pragma unroll
        for (int ks = 0; ks < 2; ++ks) {
            const int base = ks * 4 + q * 2;
            #pragma unroll
            for (int mt = 0; mt < 2; ++mt) {
                int row = wm * 64 + mt * 32 + ml;
                int sw = (row ^ (row >> 3)) & 7;
                int mb = row * 64;
                ah[ks][mt]  = *(const h8*)&Asl[buf][mb + (((base + 0) ^ sw) * 8)];
                al2[ks][mt] = *(const h8*)&Asl[buf][mb + (((base + 1) ^ sw) * 8)];
            }
            #pragma unroll
            for (int nt = 0; nt < 2; ++nt) {
                int col = wn * 64 + nt * 32 + ml;
                int sw = (col ^ (col >> 3)) & 7;
                int nb = col * 64;
                bh2[ks][nt] = *(const h8*)&Bsl[buf][nb + (((base + 0) ^ sw) * 8)];
                bl2[ks][nt] = *(const h8*)&Bsl[buf][nb + (((base + 1) ^ sw) * 8)];
            }
        }
        asm volatile("s_waitcnt lgkmcnt(0)" ::: "memory");  // my reads retired
        __builtin_amdgcn_sched_barrier(0);
        __builtin_amdgcn_s_barrier();                       // everyone's reads retired
        // ---- phase B: refill the buffer just freed (loads fly during MFMAs)
        if (kt + 2 < NT) stage(kt + 2, buf);
        // ---- phase C: compute
        #pragma unroll
        for (int ks = 0; ks < 2; ++ks) {
            h8 ahs[2], bhs[2];
            #pragma unroll
            for (int mt = 0; mt < 2; ++mt) ahs[mt] = ah[ks][mt] * SC;
            #pragma unroll
            for (int nt = 0; nt < 2; ++nt) bhs[nt] = bh2[ks][nt] * SC;
            #pragma unroll
            for (int mt = 0; mt < 2; ++mt)
                #pragma unroll
                for (int nt = 0; nt < 2; ++nt) {
                    acc[mt][nt] = __builtin_amdgcn_mfma_f32_32x32x16_f16(ah[ks][mt],  bh2[ks][nt], acc[mt][nt], 0, 0, 0);
                    acc[mt][nt] = __builtin_amdgcn_mfma_f32_32x32x16_f16(ahs[mt],     bl2[ks][nt], acc[mt][nt], 0, 0, 0);
                    acc[mt][nt] = __builtin_amdgcn_mfma_f32_32x32x16_f16(al2[ks][mt], bhs[nt],     acc[mt][nt], 0, 0, 0);
                }
        }
        // ---- phase D: wait for NEXT buffer's loads (counted, not drained)
        if (kt + 1 < NT) {
            if (kt + 2 < NT) {
                asm volatile("s_waitcnt vmcnt(8)" ::: "memory");  // kt+1's 8 loads done
            } else {
                asm volatile("s_waitcnt vmcnt(0)" ::: "memory");  // tail: no kt+2 in flight
            }
            __builtin_amdgcn_sched_barrier(0);
            __builtin_amdgcn_s_barrier();
        }
    }

    // epilogue: C/D layout col=lane&31, row=(g&3)+8*(g>>2)+4*q  [m74/m101]
    #pragma unroll
    for (int mt = 0; mt < 2; ++mt)
        #pragma unroll
        for (int nt = 0; nt < 2; ++nt) {
            #pragma unroll
            for (int g = 0; g < 16; ++g) {
                int rl = wm * 64 + mt * 32 + (g & 3) + 8 * (g >> 2) + 4 * q;
                int mrow = m0 + rl;
                if (mrow < cnt) {
                    int col = n0 + wn * 64 + nt * 32 + ml;
                    size_t addr = (size_t)(off + mrow) * CD + col;
                    float v = acc[mt][nt][g];
                    if constexpr (MODE == 0) {
                        BxOut[addr] = v;
                        float z = softt(v, th);
                        _Float16 a, b;
                        fsplit(z, a, b);
                        zh[addr] = a; zl[addr] = b;
                    } else if constexpr (MODE == 1) {
                        float z = softt(v + BxBuf[addr], th);
                        _Float16 a, b;
                        fsplit(z, a, b);
                        zh[addr] = a; zl[addr] = b;
                    } else {
                        zf[addr] = softt(v + BxBuf[addr], th);
                    }
                }
            }
        }
}

// ---------------- K6+K7 fused: per-wave top-k prune + h = b1 + sparse_z@W1, then
// BLOCK-COOPERATIVE out = relu(h)@W2 + b2. [R1: 4x W2 L2-traffic reduction]
// [R8] bit-search early exit: when count(>=cand)==lvl exactly, {ab>=cand} is
// provably identical to {ab>=kth-largest} (no elements in [cand,v_lvl); ties at
// v_lvl would force count>lvl). Typical exit after ~10-14 of 31 iterations.
__global__ __launch_bounds__(256)
void k_po(const float* __restrict__ z, const int* __restrict__ offsets,
          const float* __restrict__ W1, const float* __restrict__ b1,
          const float* __restrict__ W2, const float* __restrict__ b2,
          const int* __restrict__ perm, float* __restrict__ out) {
    const int SL[KE] = {5, 150, 296, 441, 587, 732, 878, 1024};
    __shared__ float vLg[4][PCAP];   // 2.5 KB
    __shared__ int   iLg[4][PCAP];   // 2.5 KB
    __shared__ float hSg[4][CD];     // 16 KB; doubles as dense pruned-z staging
    __shared__ float prt[4][4][64];  // 4 KB [wave][row][lane] partial sums
    const int t = threadIdx.x;
    const int lane = t & 63;
    const int wv = t >> 6;
    const int slot = blockIdx.x * 4 + wv;
    float* vL = vLg[wv];
    int* iLs = iLg[wv];
    float* hS = hSg[wv];

    int k = 0;
    #pragma unroll
    for (int e = 1; e < KE; ++e)
        if (slot >= offsets[e]) k = e;
    const int lvl = SL[k];

    const float* zr = z + (size_t)slot * CD;
    float v[16];
    unsigned ab[16];
    #pragma unroll
    for (int j = 0; j < 16; ++j) {
        v[j] = zr[lane + 64 * j];
        ab[j] = __float_as_uint(fabsf(v[j]));
    }
    // exact kth-largest |z| bit pattern; count via ballot+popc; early exit on c==lvl
    unsigned thr = 0;
    for (int b = 30; b >= 0; --b) {
        unsigned cand = thr | (1u << b);
        int c = 0;
        #pragma unroll
        for (int j = 0; j < 16; ++j)
            c += __popcll(__ballot(ab[j] >= cand));
        if (c >= lvl) {
            thr = cand;
            if (c == lvl) break;  // kept set already exact (see proof above)
        }
    }
    int cnt = 0;
    #pragma unroll
    for (int j = 0; j < 16; ++j) cnt += __popcll(__ballot(ab[j] >= thr));

    float h[16];
    #pragma unroll
    for (int j = 0; j < 16; ++j) h[j] = b1[lane + 64 * j];

    if (cnt <= PCAP) {
        // compact list; iterate only cnt entries
        int base = 0;
        #pragma unroll
        for (int j = 0; j < 16; ++j) {
            bool keep = ab[j] >= thr;
            unsigned long long m = __ballot(keep);
            if (keep) {
                int pos = base + __popcll(m & ((1ULL << lane) - 1));
                vL[pos] = v[j];
                iLs[pos] = lane + 64 * j;
            }
            base += __popcll(m);
        }
        __builtin_amdgcn_wave_barrier();
        for (int e = 0; e < cnt; ++e) {
            float val = vL[e];
            const float* wr = W1 + (size_t)iLs[e] * CD;
            #pragma unroll
            for (int j = 0; j < 16; ++j)
                h[j] = fmaf(val, wr[lane + 64 * j], h[j]);
        }
    } else {
        // dense fallback: stage pruned row, multiply all CD entries (zeros are no-ops)
        #pragma unroll
        for (int j = 0; j < 16; ++j)
            hS[lane + 64 * j] = (ab[j] >= thr) ? v[j] : 0.f;
        __builtin_amdgcn_wave_barrier();
        for (int e = 0; e < CD; ++e) {
            float val = hS[e];
            const float* wr = W1 + (size_t)e * CD;
            #pragma unroll
            for (int j = 0; j < 16; ++j)
                h[j] = fmaf(val, wr[lane + 64 * j], h[j]);
        }
        __builtin_amdgcn_wave_barrier();
    }

    // relu + stage h for block-wide use
    #pragma unroll
    for (int j = 0; j < 16; ++j) hSg[wv][lane + 64 * j] = fmaxf(h[j], 0.f);
    __syncthreads();

    // cooperative W2 pass: wave wv covers i in [wv*256, wv*256+256); each W2 row
    // loaded ONCE per block and applied to all 4 rows (register reuse).
    const float* w2c = W2 + lane;
    float a[4] = {0.f, 0.f, 0.f, 0.f};
    const int i0 = wv * 256;
    #pragma unroll 4
    for (int i = i0; i < i0 + 256; i += 4) {
        float w0 = w2c[(size_t)(i + 0) * PD];
        float w1 = w2c[(size_t)(i + 1) * PD];
        float w2v = w2c[(size_t)(i + 2) * PD];
        float w3 = w2c[(size_t)(i + 3) * PD];
        #pragma unroll
        for (int r = 0; r < 4; ++r) {
            float4 hv = *(const float4*)&hSg[r][i];   // uniform addr -> LDS broadcast
            a[r] = fmaf(hv.x, w0, a[r]);
            a[r] = fmaf(hv.y, w1, a[r]);
            a[r] = fmaf(hv.z, w2v, a[r]);
            a[r] = fmaf(hv.w, w3, a[r]);
        }
    }
    #pragma unroll
    for (int r = 0; r < 4; ++r) prt[wv][r][lane] = a[r];
    __syncthreads();

    float acc = ((prt[0][wv][lane] + prt[1][wv][lane]) +
                 (prt[2][wv][lane] + prt[3][wv][lane])) + b2[lane];
    out[(size_t)perm[slot] * PD + lane] = acc;
}

extern "C" void kernel_launch(void* const* d_in, const int* in_sizes, int n_in,
                              void* d_out, int out_size, void* d_ws, size_t ws_size,
                              hipStream_t stream) {
    const float* x     = (const float*)d_in[0];
    const float* Wq    = (const float*)d_in[1];
    const float* bq    = (const float*)d_in[2];
    const float* keys  = (const float*)d_in[3];
    const float* We    = (const float*)d_in[4];
    const float* S     = (const float*)d_in[5];
    const float* theta = (const float*)d_in[6];
    const float* W1    = (const float*)d_in[7];
    const float* b1    = (const float*)d_in[8];
    const float* W2    = (const float*)d_in[9];
    const float* b2    = (const float*)d_in[10];
    float* out = (float*)d_out;

    const size_t F = (size_t)NB * CD;  // 8.39M elements
    float* Bx = (float*)d_ws;                         // region 0: F floats
    _Float16* zAh = (_Float16*)(Bx + F);              // region 1: 2F halves
    _Float16* zAl = zAh + F;
    float* R1 = (float*)(zAl + F);                    // region 2: F floats, multi-phase
    _Float16* xh  = (_Float16*)R1;
    _Float16* xl  = xh + (size_t)NB * IND;
    _Float16* weh = xl + (size_t)NB * IND;
    _Float16* wel = weh + (size_t)KE * IND * CD;
    _Float16* zBh = (_Float16*)R1;
    _Float16* zBl = zBh + F;
    float* z1 = R1;
    _Float16* sth = (_Float16*)(R1 + F);              // region 3: 2F halves
    _Float16* stl = sth + F;
    float* M  = (float*)(stl + F);
    float* sb = M + IND * KE;
    int* idx     = (int*)(sb + 8);
    int* perm    = idx + NB;
    int* counts  = perm + NB;
    int* offsets = counts + KE;

    // gating first so tsplit can skip unused experts
    k_precompute_M<<<16, 256, 0, stream>>>(Wq, keys, bq, M, sb);
    k_scores<<<NB / 4, 256, 0, stream>>>(x, M, sb, idx);
    k_count<<<1, 256, 0, stream>>>(idx, perm, counts, offsets);

    k_split_rows<<<(NB * IND) / 1024, 256, 0, stream>>>(x, xh, xl, NB * IND);
    {
        dim3 g(IND / 64, CD / 64, KE);
        k_tsplit<<<g, 256, 0, stream>>>(We, weh, wel, IND, counts);
    }
    {
        dim3 g(CD / 64, CD / 64, KE);
        k_tsplit<<<g, 256, 0, stream>>>(S, sth, stl, CD, counts);
    }

    dim3 gg(CD / 128, NB / 128, KE);
    k_mfma<IND, 0><<<gg, 256, 0, stream>>>(xh, xl, weh, wel, theta, nullptr, Bx, zAh, zAl, nullptr, perm, counts, offsets);
    k_mfma<CD, 1><<<gg, 256, 0, stream>>>(zAh, zAl, sth, stl, theta, Bx, nullptr, zBh, zBl, nullptr, perm, counts, offsets);
    k_mfma<CD, 1><<<gg, 256, 0, stream>>>(zBh, zBl, sth, stl, theta, Bx, nullptr, zAh, zAl, nullptr, perm, counts, offsets);
    k_mfma<CD, 1><<<gg, 256, 0, stream>>>(zAh, zAl, sth, stl, theta, Bx, nullptr, zBh, zBl, nullptr, perm, counts, offsets);
    k_mfma<CD, 1><<<gg, 256, 0, stream>>>(zBh, zBl, sth, stl, theta, Bx, nullptr, zAh, zAl, nullptr, perm, counts, offsets);
    k_mfma<CD, 2><<<gg, 256, 0, stream>>>(zAh, zAl, sth, stl, theta, Bx, nullptr, nullptr, nullptr, z1, perm, counts, offsets);

    k_po<<<NB / 4, 256, 0, stream>>>(z1, offsets, W1, b1, W2, b2, perm, out);
}

// Round 10
// 575.639 us; speedup vs baseline: 1.7037x; 1.0507x over previous
//
#include <hip/hip_runtime.h>
#include <math.h>

#define NB 8192
#define IND 512
#define QDIM 128
#define CD 1024
#define KE 8
#define PD 64
#define PCAP 160  // compact-list capacity per row (covers sparsity levels 5,150)

typedef _Float16 h8 __attribute__((ext_vector_type(8)));
typedef _Float16 h4 __attribute__((ext_vector_type(4)));
typedef float fx16 __attribute__((ext_vector_type(16)));

#define GLD16(g, l) __builtin_amdgcn_global_load_lds((const __attribute__((address_space(1))) void*)(g), (__attribute__((address_space(3))) void*)(l), 16, 0, 0)

__device__ __forceinline__ float softt(float v, float th) {
    float a = fabsf(v) - th;
    return a > 0.0f ? copysignf(a, v) : 0.0f;
}

// ---------------- split helpers: v = hi + lo * 2^-11 (lo stored pre-scaled by 2048)
// [R7 lesson] BOTH GEMM operands must keep the full hi/lo split: single-fp16 B gave
// z-error ~1e-3 which flipped top-k selection in ~hundreds of rows (5th/6th |z| gap
// ~0.03) -> absmax 0.069 FAIL. Split (rel err 2^-22) keeps selection exact.
__device__ __forceinline__ void fsplit(float v, _Float16& hi, _Float16& lo) {
    hi = (_Float16)v;
    lo = (_Float16)((v - (float)hi) * 2048.0f);
}

// ---------------- K0: M = Wq @ keys^T / sqrt(QDIM), sb = bq @ keys^T / sqrt(QDIM)
__global__ void k_precompute_M(const float* __restrict__ Wq, const float* __restrict__ keys,
                               const float* __restrict__ bq, float* __restrict__ M,
                               float* __restrict__ sb) {
    const float RSQ = 0.088388347648318447f; // 1/sqrt(128)
    int g = blockIdx.x * 256 + threadIdx.x;  // 0..4095
    if (g < IND * KE) {
        int i = g >> 3, k = g & 7;
        float s = 0.f;
        for (int q = 0; q < QDIM; ++q) s += Wq[i * QDIM + q] * keys[k * QDIM + q];
        M[g] = s * RSQ;  // M[i*8+k]
    }
    if (blockIdx.x == 0 && threadIdx.x < KE) {
        int k = threadIdx.x;
        float s = 0.f;
        for (int q = 0; q < QDIM; ++q) s += bq[q] * keys[k * QDIM + q];
        sb[k] = s * RSQ;
    }
}

// ---------------- K1: per-row scores -> expert idx (one wave per row, no atomics)
__global__ __launch_bounds__(256)
void k_scores(const float* __restrict__ x, const float* __restrict__ M,
              const float* __restrict__ sb, int* __restrict__ idx) {
    __shared__ float Ms[KE][IND];
    __shared__ float sbs[KE];
    int t = threadIdx.x;
    #pragma unroll
    for (int j = 0; j < 16; ++j) {
        int e = j * 256 + t;
        Ms[e & 7][e >> 3] = M[e];
    }
    if (t < KE) sbs[t] = sb[t];
    __syncthreads();
    int w = t >> 6, lane = t & 63;
    int row = blockIdx.x * 4 + w;
    const float* xr = x + (size_t)row * IND;
    float sc[KE];
    #pragma unroll
    for (int k = 0; k < KE; ++k) sc[k] = 0.f;
    #pragma unroll
    for (int j = 0; j < IND / 64; ++j) {
        int ii = lane + 64 * j;
        float xv = xr[ii];
        #pragma unroll
        for (int k = 0; k < KE; ++k) sc[k] += xv * Ms[k][ii];
    }
    #pragma unroll
    for (int k = 0; k < KE; ++k) {
        #pragma unroll
        for (int off = 32; off >= 1; off >>= 1) sc[k] += __shfl_down(sc[k], off, 64);
    }
    if (lane == 0) {
        float smax = -1e30f;
        #pragma unroll
        for (int k = 0; k < KE; ++k) { sc[k] += sbs[k]; smax = fmaxf(smax, sc[k]); }
        const float LN09 = -0.105360515657826301f;  // ln(0.9)
        int e = 0;
        #pragma unroll
        for (int k = KE - 1; k >= 0; --k)
            if (sc[k] >= smax + LN09) e = k;  // smallest eligible k (sl is increasing)
        idx[row] = e;
    }
}

// ---------------- K2: single-block counting sort: counts, offsets, perm (no global atomics)
__global__ __launch_bounds__(256)
void k_count(const int* __restrict__ idx, int* __restrict__ perm,
             int* __restrict__ counts, int* __restrict__ offsets) {
    __shared__ int hist[256][KE];      // 8 KB
    __shared__ int sc[2][KE][256];     // 16 KB ping-pong scan
    __shared__ int base[KE];
    const int t = threadIdx.x;
    int pc[KE];
    #pragma unroll
    for (int e = 0; e < KE; ++e) pc[e] = 0;
    for (int j = 0; j < NB / 256; ++j) pc[idx[j * 256 + t]]++;
    #pragma unroll
    for (int e = 0; e < KE; ++e) { hist[t][e] = pc[e]; sc[0][e][t] = pc[e]; }
    __syncthreads();
    int cur = 0;
    for (int d = 1; d < 256; d <<= 1) {
        #pragma unroll
        for (int e = 0; e < KE; ++e) {
            int v = sc[cur][e][t];
            if (t >= d) v += sc[cur][e][t - d];
            sc[cur ^ 1][e][t] = v;
        }
        cur ^= 1;
        __syncthreads();
    }
    if (t == 0) {
        int a = 0;
        #pragma unroll
        for (int e = 0; e < KE; ++e) {
            int tot = sc[cur][e][255];
            base[e] = a; offsets[e] = a; counts[e] = tot; a += tot;
        }
    }
    __syncthreads();
    int pos[KE];
    #pragma unroll
    for (int e = 0; e < KE; ++e) pos[e] = base[e] + sc[cur][e][t] - hist[t][e];
    for (int j = 0; j < NB / 256; ++j) {
        int r = j * 256 + t;
        int e = idx[r];
        perm[pos[e]++] = r;
    }
}

// ---------------- K4: elementwise split of x into hi/lo fp16 planes
__global__ __launch_bounds__(256)
void k_split_rows(const float* __restrict__ src, _Float16* __restrict__ ph,
                  _Float16* __restrict__ pl, int n) {
    int i = (blockIdx.x * 256 + threadIdx.x) * 4;
    if (i < n) {
        float4 v = *(const float4*)(src + i);
        h4 hh, ll;
        #pragma unroll
        for (int j = 0; j < 4; ++j) {
            _Float16 a, b;
            fsplit((&v.x)[j], a, b);
            hh[j] = a; ll[j] = b;
        }
        *(h4*)(ph + i) = hh;
        *(h4*)(pl + i) = ll;
    }
}

// ---------------- K5: transpose+split: src[e][K][CD] fp32 -> th/tl[e][CD][K] fp16
// Skips experts with zero selected rows (counts from k_count — launch-ordered before).
__global__ __launch_bounds__(256)
void k_tsplit(const float* __restrict__ src, _Float16* __restrict__ th,
              _Float16* __restrict__ tl, int K, const int* __restrict__ counts) {
    int e = blockIdx.z;
    if (counts[e] == 0) return;  // expert never used downstream
    __shared__ float tile[64][65];
    int k0 = blockIdx.x * 64;
    int n0 = blockIdx.y * 64;
    const float* s = src + (size_t)e * K * CD;
    int t = threadIdx.x;
    int tr = t >> 4;
    int tc = (t & 15) * 4;
    #pragma unroll
    for (int p = 0; p < 4; ++p) {
        int kk = tr + p * 16;
        float4 v = *(const float4*)&s[(size_t)(k0 + kk) * CD + n0 + tc];
        #pragma unroll
        for (int j = 0; j < 4; ++j) tile[kk][tc + j] = (&v.x)[j];
    }
    __syncthreads();
    int n = t >> 2;
    int kq = (t & 3) * 16;
    h8 hh0, hh1, ll0, ll1;
    #pragma unroll
    for (int j = 0; j < 8; ++j) {
        _Float16 a, b;
        fsplit(tile[kq + j][n], a, b);
        hh0[j] = a; ll0[j] = b;
        fsplit(tile[kq + 8 + j][n], a, b);
        hh1[j] = a; ll1[j] = b;
    }
    size_t ob = ((size_t)e * CD + n0 + n) * K + k0 + kq;
    *(h8*)(th + ob) = hh0;
    *(h8*)(th + ob + 8) = hh1;
    *(h8*)(tl + ob) = ll0;
    *(h8*)(tl + ob + 8) = ll1;
}

// ---------------- grouped split-fp16 MFMA GEMM, 128x128 tile, BK=32.
// [R10] 8-WAVE blocks (512 thr) on the R4/R9 structure. R9 accounting: 6000
// cyc/iter/block; MFMA 1770 (29% = MfmaUtil), VALU 1320, LDS ~2000 — phases run
// SERIALLY because 2 waves/SIMD can't overlap one wave's LDS phase with
// another's MFMA. Grid is fixed at 512 working blocks (2/CU); the untried TLP
// axis is waves/block: 8 waves -> 16 waves/CU = 4/SIMD. Wave grid 4x2, wave
// tile 32x64 (acc 32 VGPR; __launch_bounds__(512,4) caps at 128 VGPR).
// Counted-vmcnt pipeline (T4) unchanged: 2-deep prefetch, per iter:
//   ds_reads -> lgkmcnt(0) -> s_barrier -> stage(kt+2) into freed buf
//   -> MFMAs -> vmcnt(4) [never 0 until tail] -> s_barrier
// sched_barrier(0) after each asm wait (rule #18). Single accumulator via exact
// 2^-11 operand pre-scale. Bank swizzle g(r)=(r^(r>>3))&7, 0 conflicts measured.
// [R5/R6/R7 post-mortems] LDS-free direct loads: -2x; 64² tile: -1.5x;
// B single-fp16: FAIL (top-k selection flips). Full split is load-bearing.
template <int KDIM, int MODE>
__global__ __launch_bounds__(512, 4)
void k_mfma(const _Float16* __restrict__ Ah, const _Float16* __restrict__ Al,
            const _Float16* __restrict__ Bh, const _Float16* __restrict__ Bl,
            const float* __restrict__ theta, const float* __restrict__ BxBuf,
            float* __restrict__ BxOut, _Float16* __restrict__ zh, _Float16* __restrict__ zl,
            float* __restrict__ zf,
            const int* __restrict__ perm, const int* __restrict__ counts,
            const int* __restrict__ offsets) {
    const int e = blockIdx.z;
    const int cnt = counts[e];
    const int p = blockIdx.x + 8 * blockIdx.y;
    const int gx = p & 7;
    const int qq = p >> 3;
    const int bxl = qq & 7;
    const int byl = gx + 8 * (qq >> 3);
    const int m0 = byl * 128;
    if (m0 >= cnt) return;
    const int n0 = bxl * 128;
    const int off = offsets[e];
    const float th = theta[e];

    __shared__ _Float16 Asl[2][128 * 64];  // 16 KB per buffer
    __shared__ _Float16 Bsl[2][128 * 64];

    const int t = threadIdx.x;
    const int lane = t & 63;
    const int w = t >> 6;                  // 0..7

    // staging: 16 chunks of 8 rows; chunk s = w*2+i, 8 lanes/row x 16B
    const _Float16* aptr[2];
    const _Float16* bptr[2];
    #pragma unroll
    for (int i = 0; i < 2; ++i) {
        int s = w * 2 + i;
        int r = s * 8 + (lane >> 3);
        int pc = lane & 7;
        int lc = pc ^ ((r ^ (r >> 3)) & 7);
        int comp = lc & 1;
        int kg = lc >> 1;
        int mrow = m0 + r; if (mrow > cnt - 1) mrow = cnt - 1;
        size_t grow;
        if constexpr (MODE == 0) grow = (size_t)perm[off + mrow];
        else grow = (size_t)(off + mrow);
        aptr[i] = (comp ? Al : Ah) + grow * KDIM + kg * 8;
        bptr[i] = (comp ? Bl : Bh) + ((size_t)e * CD + n0 + r) * KDIM + kg * 8;
    }

    const int wm = w >> 1, wn = w & 1;     // wm 0..3 (32-row stripes), wn 0..1
    const int q = lane >> 5;
    const int ml = lane & 31;

    fx16 acc[2];
    #pragma unroll
    for (int nt = 0; nt < 2; ++nt)
        #pragma unroll
        for (int g = 0; g < 16; ++g) acc[nt][g] = 0.f;

    auto stage = [&](int kt, int buf) {
        const int koff = kt * 32;
        #pragma unroll
        for (int i = 0; i < 2; ++i) {
            GLD16(aptr[i] + koff, &Asl[buf][(w * 2 + i) * 512]);
            GLD16(bptr[i] + koff, &Bsl[buf][(w * 2 + i) * 512]);
        }
    };

    const _Float16 SC = (_Float16)4.8828125e-4f;  // 2^-11, exact exponent shift

    const int NT = KDIM / 32;
    stage(0, 0);
    stage(1, 1);
    asm volatile("s_waitcnt vmcnt(4)" ::: "memory");  // stage(0)'s 4 loads done
    __builtin_amdgcn_sched_barrier(0);
    __builtin_amdgcn_s_barrier();

    for (int kt = 0; kt < NT; ++kt) {
        const int buf = kt & 1;
        // ---- phase A: LDS -> registers (both k-slices)
        h8 ah[2], al2[2], bh2[2][2], bl2[2][2];  // [ks] / [ks][nt]
        #pragma unroll
        for (int ks = 0; ks < 2; ++ks) {
            const int base = ks * 4 + q * 2;
            {
                int row = wm * 32 + ml;
                int sw = (row ^ (row >> 3)) & 7;
                int mb = row * 64;
                ah[ks]  = *(const h8*)&Asl[buf][mb + (((base + 0) ^ sw) * 8)];
                al2[ks] = *(const h8*)&Asl[buf][mb + (((base + 1) ^ sw) * 8)];
            }
            #pragma unroll
            for (int nt = 0; nt < 2; ++nt) {
                int col = wn * 64 + nt * 32 + ml;
                int sw = (col ^ (col >> 3)) & 7;
                int nb = col * 64;
                bh2[ks][nt] = *(const h8*)&Bsl[buf][nb + (((base + 0) ^ sw) * 8)];
                bl2[ks][nt] = *(const h8*)&Bsl[buf][nb + (((base + 1) ^ sw) * 8)];
            }
        }
        asm volatile("s_waitcnt lgkmcnt(0)" ::: "memory");  // my reads retired
        __builtin_amdgcn_sched_barrier(0);
        __builtin_amdgcn_s_barrier();                       // everyone's reads retired
        // ---- phase B: refill the buffer just freed (loads fly during MFMAs)
        if (kt + 2 < NT) stage(kt + 2, buf);
        // ---- phase C: compute
        #pragma unroll
        for (int ks = 0; ks < 2; ++ks) {
            h8 ahs = ah[ks] * SC;
            h8 bhs[2];
            #pragma unroll
            for (int nt = 0; nt < 2; ++nt) bhs[nt] = bh2[ks][nt] * SC;
            #pragma unroll
            for (int nt = 0; nt < 2; ++nt) {
                acc[nt] = __builtin_amdgcn_mfma_f32_32x32x16_f16(ah[ks],  bh2[ks][nt], acc[nt], 0, 0, 0);
                acc[nt] = __builtin_amdgcn_mfma_f32_32x32x16_f16(ahs,     bl2[ks][nt], acc[nt], 0, 0, 0);
                acc[nt] = __builtin_amdgcn_mfma_f32_32x32x16_f16(al2[ks], bhs[nt],     acc[nt], 0, 0, 0);
            }
        }
        // ---- phase D: wait for NEXT buffer's loads (counted, not drained)
        if (kt + 1 < NT) {
            if (kt + 2 < NT) {
                asm volatile("s_waitcnt vmcnt(4)" ::: "memory");  // kt+1's 4 loads done
            } else {
                asm volatile("s_waitcnt vmcnt(0)" ::: "memory");  // tail: no kt+2 in flight
            }
            __builtin_amdgcn_sched_barrier(0);
            __builtin_amdgcn_s_barrier();
        }
    }

    // epilogue: C/D layout col=lane&31, row=(g&3)+8*(g>>2)+4*q  [m74/m101]
    #pragma unroll
    for (int nt = 0; nt < 2; ++nt) {
        #pragma unroll
        for (int g = 0; g < 16; ++g) {
            int rl = wm * 32 + (g & 3) + 8 * (g >> 2) + 4 * q;
            int mrow = m0 + rl;
            if (mrow < cnt) {
                int col = n0 + wn * 64 + nt * 32 + ml;
                size_t addr = (size_t)(off + mrow) * CD + col;
                float v = acc[nt][g];
                if constexpr (MODE == 0) {
                    BxOut[addr] = v;
                    float z = softt(v, th);
                    _Float16 a, b;
                    fsplit(z, a, b);
                    zh[addr] = a; zl[addr] = b;
                } else if constexpr (MODE == 1) {
                    float z = softt(v + BxBuf[addr], th);
                    _Float16 a, b;
                    fsplit(z, a, b);
                    zh[addr] = a; zl[addr] = b;
                } else {
                    zf[addr] = softt(v + BxBuf[addr], th);
                }
            }
        }
    }
}

// ---------------- K6+K7 fused: per-wave top-k prune + h = b1 + sparse_z@W1, then
// BLOCK-COOPERATIVE out = relu(h)@W2 + b2. [R1: 4x W2 L2-traffic reduction]
// [R8] bit-search early exit: when count(>=cand)==lvl exactly, {ab>=cand} is
// provably identical to {ab>=kth-largest} (no elements in [cand,v_lvl); ties at
// v_lvl would force count>lvl). Typical exit after ~10-14 of 31 iterations.
__global__ __launch_bounds__(256)
void k_po(const float* __restrict__ z, const int* __restrict__ offsets,
          const float* __restrict__ W1, const float* __restrict__ b1,
          const float* __restrict__ W2, const float* __restrict__ b2,
          const int* __restrict__ perm, float* __restrict__ out) {
    const int SL[KE] = {5, 150, 296, 441, 587, 732, 878, 1024};
    __shared__ float vLg[4][PCAP];   // 2.5 KB
    __shared__ int   iLg[4][PCAP];   // 2.5 KB
    __shared__ float hSg[4][CD];     // 16 KB; doubles as dense pruned-z staging
    __shared__ float prt[4][4][64];  // 4 KB [wave][row][lane] partial sums
    const int t = threadIdx.x;
    const int lane = t & 63;
    const int wv = t >> 6;
    const int slot = blockIdx.x * 4 + wv;
    float* vL = vLg[wv];
    int* iLs = iLg[wv];
    float* hS = hSg[wv];

    int k = 0;
    #pragma unroll
    for (int e = 1; e < KE; ++e)
        if (slot >= offsets[e]) k = e;
    const int lvl = SL[k];

    const float* zr = z + (size_t)slot * CD;
    float v[16];
    unsigned ab[16];
    #pragma unroll
    for (int j = 0; j < 16; ++j) {
        v[j] = zr[lane + 64 * j];
        ab[j] = __float_as_uint(fabsf(v[j]));
    }
    // exact kth-largest |z| bit pattern; count via ballot+popc; early exit on c==lvl
    unsigned thr = 0;
    for (int b = 30; b >= 0; --b) {
        unsigned cand = thr | (1u << b);
        int c = 0;
        #pragma unroll
        for (int j = 0; j < 16; ++j)
            c += __popcll(__ballot(ab[j] >= cand));
        if (c >= lvl) {
            thr = cand;
            if (c == lvl) break;  // kept set already exact (see proof above)
        }
    }
    int cnt = 0;
    #pragma unroll
    for (int j = 0; j < 16; ++j) cnt += __popcll(__ballot(ab[j] >= thr));

    float h[16];
    #pragma unroll
    for (int j = 0; j < 16; ++j) h[j] = b1[lane + 64 * j];

    if (cnt <= PCAP) {
        // compact list; iterate only cnt entries
        int base = 0;
        #pragma unroll
        for (int j = 0; j < 16; ++j) {
            bool keep = ab[j] >= thr;
            unsigned long long m = __ballot(keep);
            if (keep) {
                int pos = base + __popcll(m & ((1ULL << lane) - 1));
                vL[pos] = v[j];
                iLs[pos] = lane + 64 * j;
            }
            base += __popcll(m);
        }
        __builtin_amdgcn_wave_barrier();
        for (int e = 0; e < cnt; ++e) {
            float val = vL[e];
            const float* wr = W1 + (size_t)iLs[e] * CD;
            #pragma unroll
            for (int j = 0; j < 16; ++j)
                h[j] = fmaf(val, wr[lane + 64 * j], h[j]);
        }
    } else {
        // dense fallback: stage pruned row, multiply all CD entries (zeros are no-ops)
        #pragma unroll
        for (int j = 0; j < 16; ++j)
            hS[lane + 64 * j] = (ab[j] >= thr) ? v[j] : 0.f;
        __builtin_amdgcn_wave_barrier();
        for (int e = 0; e < CD; ++e) {
            float val = hS[e];
            const float* wr = W1 + (size_t)e * CD;
            #pragma unroll
            for (int j = 0; j < 16; ++j)
                h[j] = fmaf(val, wr[lane + 64 * j], h[j]);
        }
        __builtin_amdgcn_wave_barrier();
    }

    // relu + stage h for block-wide use
    #pragma unroll
    for (int j = 0; j < 16; ++j) hSg[wv][lane + 64 * j] = fmaxf(h[j], 0.f);
    __syncthreads();

    // cooperative W2 pass: wave wv covers i in [wv*256, wv*256+256); each W2 row
    // loaded ONCE per block and applied to all 4 rows (register reuse).
    const float* w2c = W2 + lane;
    float a[4] = {0.f, 0.f, 0.f, 0.f};
    const int i0 = wv * 256;
    #pragma unroll 4
    for (int i = i0; i < i0 + 256; i += 4) {
        float w0 = w2c[(size_t)(i + 0) * PD];
        float w1 = w2c[(size_t)(i + 1) * PD];
        float w2v = w2c[(size_t)(i + 2) * PD];
        float w3 = w2c[(size_t)(i + 3) * PD];
        #pragma unroll
        for (int r = 0; r < 4; ++r) {
            float4 hv = *(const float4*)&hSg[r][i];   // uniform addr -> LDS broadcast
            a[r] = fmaf(hv.x, w0, a[r]);
            a[r] = fmaf(hv.y, w1, a[r]);
            a[r] = fmaf(hv.z, w2v, a[r]);
            a[r] = fmaf(hv.w, w3, a[r]);
        }
    }
    #pragma unroll
    for (int r = 0; r < 4; ++r) prt[wv][r][lane] = a[r];
    __syncthreads();

    float acc = ((prt[0][wv][lane] + prt[1][wv][lane]) +
                 (prt[2][wv][lane] + prt[3][wv][lane])) + b2[lane];
    out[(size_t)perm[slot] * PD + lane] = acc;
}

extern "C" void kernel_launch(void* const* d_in, const int* in_sizes, int n_in,
                              void* d_out, int out_size, void* d_ws, size_t ws_size,
                              hipStream_t stream) {
    const float* x     = (const float*)d_in[0];
    const float* Wq    = (const float*)d_in[1];
    const float* bq    = (const float*)d_in[2];
    const float* keys  = (const float*)d_in[3];
    const float* We    = (const float*)d_in[4];
    const float* S     = (const float*)d_in[5];
    const float* theta = (const float*)d_in[6];
    const float* W1    = (const float*)d_in[7];
    const float* b1    = (const float*)d_in[8];
    const float* W2    = (const float*)d_in[9];
    const float* b2    = (const float*)d_in[10];
    float* out = (float*)d_out;

    const size_t F = (size_t)NB * CD;  // 8.39M elements
    float* Bx = (float*)d_ws;                         // region 0: F floats
    _Float16* zAh = (_Float16*)(Bx + F);              // region 1: 2F halves
    _Float16* zAl = zAh + F;
    float* R1 = (float*)(zAl + F);                    // region 2: F floats, multi-phase
    _Float16* xh  = (_Float16*)R1;
    _Float16* xl  = xh + (size_t)NB * IND;
    _Float16* weh = xl + (size_t)NB * IND;
    _Float16* wel = weh + (size_t)KE * IND * CD;
    _Float16* zBh = (_Float16*)R1;
    _Float16* zBl = zBh + F;
    float* z1 = R1;
    _Float16* sth = (_Float16*)(R1 + F);              // region 3: 2F halves
    _Float16* stl = sth + F;
    float* M  = (float*)(stl + F);
    float* sb = M + IND * KE;
    int* idx     = (int*)(sb + 8);
    int* perm    = idx + NB;
    int* counts  = perm + NB;
    int* offsets = counts + KE;

    // gating first so tsplit can skip unused experts
    k_precompute_M<<<16, 256, 0, stream>>>(Wq, keys, bq, M, sb);
    k_scores<<<NB / 4, 256, 0, stream>>>(x, M, sb, idx);
    k_count<<<1, 256, 0, stream>>>(idx, perm, counts, offsets);

    k_split_rows<<<(NB * IND) / 1024, 256, 0, stream>>>(x, xh, xl, NB * IND);
    {
        dim3 g(IND / 64, CD / 64, KE);
        k_tsplit<<<g, 256, 0, stream>>>(We, weh, wel, IND, counts);
    }
    {
        dim3 g(CD / 64, CD / 64, KE);
        k_tsplit<<<g, 256, 0, stream>>>(S, sth, stl, CD, counts);
    }

    dim3 gg(CD / 128, NB / 128, KE);
    k_mfma<IND, 0><<<gg, 512, 0, stream>>>(xh, xl, weh, wel, theta, nullptr, Bx, zAh, zAl, nullptr, perm, counts, offsets);
    k_mfma<CD, 1><<<gg, 512, 0, stream>>>(zAh, zAl, sth, stl, theta, Bx, nullptr, zBh, zBl, nullptr, perm, counts, offsets);
    k_mfma<CD, 1><<<gg, 512, 0, stream>>>(zBh, zBl, sth, stl, theta, Bx, nullptr, zAh, zAl, nullptr, perm, counts, offsets);
    k_mfma<CD, 1><<<gg, 512, 0, stream>>>(zAh, zAl, sth, stl, theta, Bx, nullptr, zBh, zBl, nullptr, perm, counts, offsets);
    k_mfma<CD, 1><<<gg, 512, 0, stream>>>(zBh, zBl, sth, stl, theta, Bx, nullptr, zAh, zAl, nullptr, perm, counts, offsets);
    k_mfma<CD, 2><<<gg, 512, 0, stream>>>(zAh, zAl, sth, stl, theta, Bx, nullptr, nullptr, nullptr, z1, perm, counts, offsets);

    k_po<<<NB / 4, 256, 0, stream>>>(z1, offsets, W1, b1, W2, b2, perm, out);
}